// Round 13
// baseline (1731.067 us; speedup 1.0000x reference)
//
#include <hip/hip_runtime.h>
#include <cstdint>
#include <cstddef>

// ---------------- problem constants ----------------
#define EPSV 1e-5f
constexpr int Bn  = 4;
constexpr int Nn  = 32768;
constexpr int Cn  = 64;
constexpr int NSn = 16;
constexpr int On  = 128;
constexpr int Pn  = 32;                        // points per main block
constexpr int MAIN_BLOCKS = Bn * (Nn / Pn);    // 4096

typedef __attribute__((ext_vector_type(8))) short short8;   // 8 bf16 (4 VGPRs)
typedef __attribute__((ext_vector_type(4))) float f32x4;

static __device__ __forceinline__ unsigned short f2bf(float f) {
  union { float f; unsigned u; } v; v.f = f;
  unsigned r = v.u + 0x7fffu + ((v.u >> 16) & 1u);   // RNE
  return (unsigned short)(r >> 16);
}
static __device__ __forceinline__ unsigned pack2(unsigned short a, unsigned short b) {
  return (unsigned)a | ((unsigned)b << 16);
}

// ---------------- workspace layout (bytes) ----------------
constexpr size_t WS_FEATT = 0;                        // bf16 featT[B][N][64]  : 16 MB
constexpr size_t WS_WFP   = 16u * 1024 * 1024;        // bf16 packed Wf frags  : 1 MB
constexpr size_t WS_PF    = 17u * 1024 * 1024;        // f32 folded params
constexpr size_t WS_W2F   = WS_PF + 4096;             // bf16 64x64 (inv2-folded)
constexpr size_t WS_W3B   = WS_W2F + 8192;            // bf16 64x64
constexpr size_t WS_WG    = 18u * 1024 * 1024;        // bf16 weights slice (adaptive)
constexpr size_t WG_PER_BLOCK = (size_t)Pn * 1024 * 2;  // 64 KB per block-row

// pf (f32 index) layout: [0..255] W1f(64x4, inv1-folded, pad4) [256..319] b1f
// [320..383] b2f  [384..447] b3f  [448..575] bff
__global__ void k_params(const float* __restrict__ W1, const float* __restrict__ b1,
                         const float* __restrict__ g1, const float* __restrict__ be1,
                         const float* __restrict__ m1, const float* __restrict__ v1,
                         const float* __restrict__ W2, const float* __restrict__ b2,
                         const float* __restrict__ g2, const float* __restrict__ be2,
                         const float* __restrict__ m2, const float* __restrict__ v2,
                         const float* __restrict__ W3, const float* __restrict__ b3,
                         const float* __restrict__ bf_, const float* __restrict__ gf,
                         const float* __restrict__ bef, const float* __restrict__ mf,
                         const float* __restrict__ vf,
                         float* __restrict__ pf, unsigned short* __restrict__ W2f,
                         unsigned short* __restrict__ W3b) {
  int t = threadIdx.x;
  if (t < 64) {
    float inv1 = g1[t] * rsqrtf(v1[t] + EPSV);
    pf[t * 4 + 0] = W1[t * 3 + 0] * inv1;
    pf[t * 4 + 1] = W1[t * 3 + 1] * inv1;
    pf[t * 4 + 2] = W1[t * 3 + 2] * inv1;
    pf[t * 4 + 3] = 0.f;
    pf[256 + t] = b1[t] * inv1 + be1[t] - m1[t] * inv1;
    float inv2 = g2[t] * rsqrtf(v2[t] + EPSV);
    pf[320 + t] = b2[t] * inv2 + be2[t] - m2[t] * inv2;
    pf[384 + t] = b3[t];
    for (int k = 0; k < 64; ++k) {
      W2f[t * 64 + k] = f2bf(W2[t * 64 + k] * inv2);
      W3b[t * 64 + k] = f2bf(W3[t * 64 + k]);
    }
  }
  if (t < 128) {
    float invf = gf[t] * rsqrtf(vf[t] + EPSV);
    pf[448 + t] = bf_[t] * invf + bef[t] - mf[t] * invf;
  }
}

// ---------------- prep: feature (B,C,N) f32 -> featT (B,N,C) bf16 ----------------
__global__ void k_featT(const float* __restrict__ feat, unsigned short* __restrict__ featT) {
  int blk = blockIdx.x;              // 2048 = B * N/64
  int b = blk >> 9;
  int n0 = (blk & 511) << 6;
  __shared__ float tile[64][65];
  int t = threadIdx.x;
  int n_in = t & 63;
  int c4 = t >> 6;                   // 0..3
  const float* fb = feat + (size_t)b * Cn * Nn;
#pragma unroll
  for (int k = 0; k < 16; ++k) {
    int c = c4 * 16 + k;
    tile[c][n_in] = fb[(size_t)c * Nn + n0 + n_in];
  }
  __syncthreads();
  unsigned short* outp = featT + ((size_t)b * Nn + n0) * Cn;
  int cc = t & 63;
#pragma unroll
  for (int k = 0; k < 16; ++k) {
    int nn = c4 * 16 + k;
    outp[(size_t)nn * Cn + cc] = f2bf(tile[cc][nn]);
  }
}

// ---------------- prep: pack Wf*invf into B-fragment order (round-1 verified) ----
__global__ void k_wfp(const float* __restrict__ Wf, const float* __restrict__ gf,
                      const float* __restrict__ vf, unsigned short* __restrict__ WfP) {
  int e = blockIdx.x * 256 + threadIdx.x;      // 0..524287
  int rec = e >> 9, wi_ = e & 511;
  int l = wi_ >> 3, j = wi_ & 7;
  int q = rec >> 6, ks = (rec >> 3) & 7, ot = rec & 7;
  int o = ot * 16 + (l & 15);
  int kk = ks * 32 + (l >> 4) * 8 + j;
  int c = (q >> 2) * 16 + (kk >> 4);
  int w = (q & 3) * 16 + (kk & 15);
  float invf = gf[o] * rsqrtf(vf[o] + EPSV);
  WfP[e] = f2bf(Wf[(size_t)o * 4096 + c * 64 + w] * invf);
}

// ================= SPLIT PATH (adaptive slices) =================
// ---- k_wnet (R13): R12's verified 8-wave split + round-8's PER-PHASE fragment
// loads (no cross-phase hoisting -> no spill). layer1: 2048 units / 512 thr.
// layers 2/3: wave owns 32 cols. layer-3 TRANSPOSED -> coalesced wg stores.
constexpr int SMEM_WNET = 73728;

__launch_bounds__(512, 4)
__global__ void k_wnet(const float* __restrict__ xyz, const int* __restrict__ idx,
                       const float* __restrict__ pf,
                       const unsigned short* __restrict__ W2f,
                       const unsigned short* __restrict__ W3b,
                       unsigned short* __restrict__ wg, int sliceStart) {
  extern __shared__ __align__(16) char smem[];
  unsigned short* h1 = (unsigned short*)(smem);
  unsigned short* h2 = (unsigned short*)(smem + 32768);
  float4* gxbuf = (float4*)(smem + 65536);

  const int t = threadIdx.x;
  const int lane = t & 63;
  const int wv = t >> 6;
  const int lq = lane >> 4;
  const int lm = lane & 15;
  const int blkFlat = sliceStart + blockIdx.x;
  const int bb = blkFlat >> 10;
  const int n0 = (blkFlat & 1023) * Pn;
  const size_t wgBase = (size_t)blockIdx.x * Pn * 1024;  // slice-local

  const float* W1f = pf;
  const float* b1f = pf + 256;
  const f32x4 z4 = {0.f, 0.f, 0.f, 0.f};

  if (t < 256) {
    const float* xb = xyz + (size_t)bb * Nn * 3;
#pragma unroll
    for (int a = 0; a < 2; ++a) {
      int col = t + a * 256;
      int p_ = col >> 4, s_ = col & 15;
      int iv = idx[((size_t)bb * Nn + n0 + p_) * NSn + s_];
      float cx = xb[(size_t)(n0 + p_) * 3 + 0];
      float cy = xb[(size_t)(n0 + p_) * 3 + 1];
      float cz = xb[(size_t)(n0 + p_) * 3 + 2];
      gxbuf[col] = make_float4(xb[(size_t)iv * 3 + 0] - cx,
                               xb[(size_t)iv * 3 + 1] - cy,
                               xb[(size_t)iv * 3 + 2] - cz, 0.f);
    }
  }
  __syncthreads();

  for (int h = 0; h < 2; ++h) {
    // layer1 (vector): 2048 (col,oct) units over 512 threads
#pragma unroll
    for (int a = 0; a < 4; ++a) {
      int aid = t + a * 512;
      int col = aid & 255;
      int oct = aid >> 8;                    // 0..7
      float4 g = gxbuf[h * 256 + col];
      unsigned short vals[8];
#pragma unroll
      for (int jj = 0; jj < 8; ++jj) {
        int ch = oct * 8 + jj;
        float v = W1f[ch * 4 + 0] * g.x + W1f[ch * 4 + 1] * g.y +
                  W1f[ch * 4 + 2] * g.z + b1f[ch];
        vals[jj] = f2bf(fmaxf(v, 0.f));
      }
      int u = oct ^ (col & 7);
      uint4 wv4;
      wv4.x = pack2(vals[0], vals[1]); wv4.y = pack2(vals[2], vals[3]);
      wv4.z = pack2(vals[4], vals[5]); wv4.w = pack2(vals[6], vals[7]);
      *(uint4*)(h1 + (size_t)col * 64 + u * 8) = wv4;
    }
    __syncthreads();

    // layer2 GEMM: M=64 N=256 K=64; each wave owns 32 cols; frags loaded HERE
    {
      f32x4 acc2[4][2];
#pragma unroll
      for (int mt = 0; mt < 4; ++mt) { acc2[mt][0] = z4; acc2[mt][1] = z4; }
      short8 afr[4][2];
#pragma unroll
      for (int mt = 0; mt < 4; ++mt)
#pragma unroll
        for (int ks = 0; ks < 2; ++ks)
          afr[mt][ks] = *(const short8*)(W2f + (mt * 16 + lm) * 64 + ks * 32 + lq * 8);
#pragma unroll
      for (int ntl = 0; ntl < 2; ++ntl) {
        int col = wv * 32 + ntl * 16 + lm;
#pragma unroll
        for (int ks = 0; ks < 2; ++ks) {
          int u = (ks * 4 + lq) ^ (col & 7);
          short8 bfr = *(short8*)(h1 + (size_t)col * 64 + u * 8);
#pragma unroll
          for (int mt = 0; mt < 4; ++mt)
            acc2[mt][ntl] = __builtin_amdgcn_mfma_f32_16x16x32_bf16(afr[mt][ks], bfr, acc2[mt][ntl], 0, 0, 0);
        }
      }
      // bn2 + relu -> h2 (bf16 swizzled, round-8 scalar-store formula)
#pragma unroll
      for (int mt = 0; mt < 4; ++mt) {
        float4 b2v = *(const float4*)(pf + 320 + mt * 16 + lq * 4);
#pragma unroll
        for (int ntl = 0; ntl < 2; ++ntl) {
          int col = wv * 32 + ntl * 16 + lm;
          float vv[4] = {acc2[mt][ntl][0] + b2v.x, acc2[mt][ntl][1] + b2v.y,
                         acc2[mt][ntl][2] + b2v.z, acc2[mt][ntl][3] + b2v.w};
#pragma unroll
          for (int r = 0; r < 4; ++r) {
            int ch = mt * 16 + lq * 4 + r;
            float v = fmaxf(vv[r], 0.f);
            int u = (ch >> 3) ^ (col & 7);
            h2[(size_t)col * 64 + u * 8 + (ch & 7)] = f2bf(v);
          }
        }
      }
    }
    __syncthreads();

    // layer3 TRANSPOSED: D'[s][w] = mfma(A=h2-colfrag, B=W3-rowfrag); frags HERE
    {
      f32x4 acc3[4][2];
#pragma unroll
      for (int mt = 0; mt < 4; ++mt) { acc3[mt][0] = z4; acc3[mt][1] = z4; }
      short8 afr[4][2];
#pragma unroll
      for (int mt = 0; mt < 4; ++mt)
#pragma unroll
        for (int ks = 0; ks < 2; ++ks)
          afr[mt][ks] = *(const short8*)(W3b + (mt * 16 + lm) * 64 + ks * 32 + lq * 8);
#pragma unroll
      for (int ntl = 0; ntl < 2; ++ntl) {
        int col = wv * 32 + ntl * 16 + lm;
#pragma unroll
        for (int ks = 0; ks < 2; ++ks) {
          int u = (ks * 4 + lq) ^ (col & 7);
          short8 bfr = *(short8*)(h2 + (size_t)col * 64 + u * 8);
#pragma unroll
          for (int mt = 0; mt < 4; ++mt)
            acc3[mt][ntl] = __builtin_amdgcn_mfma_f32_16x16x32_bf16(bfr, afr[mt][ks], acc3[mt][ntl], 0, 0, 0);
        }
      }
      // lane holds s=lq*4+r, w=mt*16+lm -> ONE uint2/mt, coalesced 256B/wave.
      // 16-col block (wv,ntl) is exactly point p_ = h*16 + wv*2 + ntl.
#pragma unroll
      for (int ntl = 0; ntl < 2; ++ntl) {
        int p_ = h * 16 + wv * 2 + ntl;
        size_t pg = wgBase + (size_t)p_ * 1024;
#pragma unroll
        for (int mt = 0; mt < 4; ++mt) {
          float b3s = pf[384 + mt * 16 + lm];
          float v0 = acc3[mt][ntl][0] + b3s;
          float v1 = acc3[mt][ntl][1] + b3s;
          float v2 = acc3[mt][ntl][2] + b3s;
          float v3 = acc3[mt][ntl][3] + b3s;
          uint2 w2v;
          w2v.x = pack2(f2bf(v0), f2bf(v1));
          w2v.y = pack2(f2bf(v2), f2bf(v3));
          *(uint2*)(wg + pg + (lq >> 1) * 512 + (mt * 16 + lm) * 8 + (lq & 1) * 4) = w2v;
        }
      }
    }
    __syncthreads();
  }
}

// ---- k_final: round-8 VERBATIM (182 us/slice proven; VGPR 64; no swizzle).
constexpr int SMEM_FINAL = 49664;

__launch_bounds__(512, 4)
__global__ void k_final(const int* __restrict__ idx,
                        const unsigned short* __restrict__ featT,
                        const unsigned short* __restrict__ WfP,
                        const float* __restrict__ pf,
                        const unsigned short* __restrict__ wg,
                        float* __restrict__ outp, int sliceStart) {
  extern __shared__ __align__(16) char smem[];
  unsigned short* gbuf   = (unsigned short*)(smem);
  unsigned short* aggbuf = (unsigned short*)(smem + 16896);

  const int t = threadIdx.x;
  const int lane = t & 63;
  const int wv = t >> 6;
  const int lq = lane >> 4;
  const int lm = lane & 15;
  const int blkFlat = sliceStart + blockIdx.x;
  const int bb = blkFlat >> 10;
  const int n0 = (blkFlat & 1023) * Pn;

  const short8 z8 = {0, 0, 0, 0, 0, 0, 0, 0};
  const f32x4  z4 = {0.f, 0.f, 0.f, 0.f};

  // prologue: this thread's own gather index (one column per thread)
  const int p0 = t >> 4, s0 = t & 15;
  const int iv = idx[((size_t)bb * Nn + n0 + p0) * NSn + s0];
  const unsigned short* fsrc = featT + ((size_t)bb * Nn + iv) * 64;
  // slice-local af base: wbuf formula with point index relative to slice
  const unsigned short* afbase = wg + ((size_t)blockIdx.x * Pn + wv * 4) * 1024
                                    + (lq & 1) * 512 + lm * 8;

  f32x4 accY[2] = {z4, z4};

  for (int ci = 0; ci < 4; ++ci) {
    // stage gbuf[p][sh][c][8], p-stride 264 (4-way instead of 16-way conflicts)
    {
      uint4 d0 = *(const uint4*)(fsrc + ci * 16);
      uint4 d1 = *(const uint4*)(fsrc + ci * 16 + 8);
      unsigned uu[8] = {d0.x, d0.y, d0.z, d0.w, d1.x, d1.y, d1.z, d1.w};
      size_t base = (size_t)p0 * 264 + (s0 >> 3) * 128 + (s0 & 7);
#pragma unroll
      for (int k = 0; k < 8; ++k) {
        gbuf[base + (2 * k) * 8]     = (unsigned short)(uu[k] & 0xffffu);
        gbuf[base + (2 * k + 1) * 8] = (unsigned short)(uu[k] >> 16);
      }
    }
    __syncthreads();

    // B-fragment hoist (wi-invariant): lane (c=lm, k=s=(lq&1)*8+j), zero for lq>=2
    short8 bfr[4];
#pragma unroll
    for (int pp = 0; pp < 4; ++pp) {
      int p_ = wv * 4 + pp;
      short8 v = *(short8*)(gbuf + (size_t)p_ * 264 + (lq & 1) * 128 + lm * 8);
      bfr[pp] = (lq < 2) ? v : z8;
    }

#pragma unroll
    for (int wi = 0; wi < 4; ++wi) {
      int q = ci * 4 + wi;
      int buf = q & 1;
      short8 wf[8];
#pragma unroll
      for (int ks = 0; ks < 4; ++ks)
        wf[ks] = *(const short8*)(WfP + ((size_t)((q * 8 + ks) * 8 + wv)) * 512 + lane * 8);
      // agg: 4 points, one padded-K MFMA each; af straight from global wg
#pragma unroll
      for (int pp = 0; pp < 4; ++pp) {
        int p_ = wv * 4 + pp;
        short8 afv = *(const short8*)(afbase + (size_t)pp * 1024 + wi * 128);
        short8 afr = (lq < 2) ? afv : z8;
        f32x4 d = __builtin_amdgcn_mfma_f32_16x16x32_bf16(afr, bfr[pp], z4, 0, 0, 0);
        int kkb = lm * 16 + lq * 4;
        int us = (kkb >> 3) ^ (p_ & 7);
        uint2 w2v;
        w2v.x = pack2(f2bf(d[0]), f2bf(d[1]));
        w2v.y = pack2(f2bf(d[2]), f2bf(d[3]));
        *(uint2*)(aggbuf + (size_t)buf * 8192 + (size_t)p_ * 256 + us * 8 + (kkb & 7)) = w2v;
      }
      __syncthreads();
#pragma unroll
      for (int ks = 4; ks < 8; ++ks)
        wf[ks] = *(const short8*)(WfP + ((size_t)((q * 8 + ks) * 8 + wv)) * 512 + lane * 8);
      // final GEMM chunk: K=256; wave owns o-tile ot = wv
#pragma unroll
      for (int ks = 0; ks < 8; ++ks) {
#pragma unroll
        for (int mt = 0; mt < 2; ++mt) {
          int p16 = mt * 16 + lm;
          int u = (ks * 4 + lq) ^ (p16 & 7);
          short8 afr = *(const short8*)(aggbuf + (size_t)buf * 8192 + (size_t)p16 * 256 + u * 8);
          accY[mt] = __builtin_amdgcn_mfma_f32_16x16x32_bf16(afr, wf[ks], accY[mt], 0, 0, 0);
        }
      }
      // no barrier: next chunk writes the other agg buffer
    }
  }

  // epilogue: y = relu(acc + bff[o]), store (B,O,N)
  {
    int o = wv * 16 + lm;
    float bo = pf[448 + o];
#pragma unroll
    for (int mt = 0; mt < 2; ++mt) {
      f32x4 vv;
#pragma unroll
      for (int r = 0; r < 4; ++r) vv[r] = fmaxf(accY[mt][r] + bo, 0.f);
      int p_ = mt * 16 + lq * 4;
      float* dst = outp + ((size_t)bb * On + o) * Nn + n0 + p_;
      *(f32x4*)dst = vv;
    }
  }
}

// ================= FALLBACK: round-4 fused kernel (verbatim) =================
constexpr int SMEM_MAIN = 141312;

__launch_bounds__(512, 1)
__global__ void k_main(const float* __restrict__ xyz, const int* __restrict__ idx,
                       const unsigned short* __restrict__ featT,
                       const unsigned short* __restrict__ WfP,
                       const float* __restrict__ pf,
                       const unsigned short* __restrict__ W2f,
                       const unsigned short* __restrict__ W3b,
                       float* __restrict__ outp) {
  extern __shared__ __align__(16) char smem[];
  unsigned short* wbuf   = (unsigned short*)(smem);
  unsigned short* h1     = (unsigned short*)(smem + 65536);
  unsigned short* gbuf   = (unsigned short*)(smem + 65536);
  unsigned short* h2     = (unsigned short*)(smem + 98304);
  unsigned short* aggbuf = (unsigned short*)(smem + 98304);
  float4* gxbuf = (float4*)(smem + 131072);
  int*    idxbuf = (int*)(smem + 139264);

  const int t = threadIdx.x;
  const int lane = t & 63;
  const int wv = t >> 6;
  const int lq = lane >> 4;
  const int lm = lane & 15;
  const int blk = blockIdx.x;
  const int bb = blk >> 10;
  const int n0 = (blk & 1023) * Pn;

  const float* W1f = pf;
  const float* b1f = pf + 256;
  const float* b2f = pf + 320;
  const float* b3f = pf + 384;
  const float* bff = pf + 448;

  const short8 z8 = {0, 0, 0, 0, 0, 0, 0, 0};
  const f32x4  z4 = {0.f, 0.f, 0.f, 0.f};

  if (t < 256) {
    const float* xb = xyz + (size_t)bb * Nn * 3;
#pragma unroll
    for (int a = 0; a < 2; ++a) {
      int col = t + a * 256;
      int p_ = col >> 4, s_ = col & 15;
      int iv = idx[((size_t)bb * Nn + n0 + p_) * NSn + s_];
      idxbuf[col] = iv;
      float cx = xb[(size_t)(n0 + p_) * 3 + 0];
      float cy = xb[(size_t)(n0 + p_) * 3 + 1];
      float cz = xb[(size_t)(n0 + p_) * 3 + 2];
      gxbuf[col] = make_float4(xb[(size_t)iv * 3 + 0] - cx,
                               xb[(size_t)iv * 3 + 1] - cy,
                               xb[(size_t)iv * 3 + 2] - cz, 0.f);
    }
  }
  __syncthreads();

  for (int h = 0; h < 2; ++h) {
    if (wv < 4) {
#pragma unroll
      for (int a = 0; a < 8; ++a) {
        int aid = t + a * 256;
        int col = aid & 255;
        int oct = aid >> 8;
        float4 g = gxbuf[h * 256 + col];
        unsigned short vals[8];
#pragma unroll
        for (int jj = 0; jj < 8; ++jj) {
          int ch = oct * 8 + jj;
          float v = W1f[ch * 4 + 0] * g.x + W1f[ch * 4 + 1] * g.y +
                    W1f[ch * 4 + 2] * g.z + b1f[ch];
          vals[jj] = f2bf(fmaxf(v, 0.f));
        }
        int u = oct ^ (col & 7);
        uint4 wv4;
        wv4.x = pack2(vals[0], vals[1]); wv4.y = pack2(vals[2], vals[3]);
        wv4.z = pack2(vals[4], vals[5]); wv4.w = pack2(vals[6], vals[7]);
        *(uint4*)(h1 + (size_t)col * 64 + u * 8) = wv4;
      }
    }
    __syncthreads();

    if (wv < 4) {
      f32x4 acc2[4][4];
#pragma unroll
      for (int mt = 0; mt < 4; ++mt)
#pragma unroll
        for (int nt = 0; nt < 4; ++nt) acc2[mt][nt] = z4;
      short8 afr[4][2];
#pragma unroll
      for (int mt = 0; mt < 4; ++mt)
#pragma unroll
        for (int ks = 0; ks < 2; ++ks)
          afr[mt][ks] = *(const short8*)(W2f + (mt * 16 + lm) * 64 + ks * 32 + lq * 8);
#pragma unroll
      for (int nt = 0; nt < 4; ++nt) {
        int col = wv * 64 + nt * 16 + lm;
#pragma unroll
        for (int ks = 0; ks < 2; ++ks) {
          int u = (ks * 4 + lq) ^ (col & 7);
          short8 bfr = *(short8*)(h1 + (size_t)col * 64 + u * 8);
#pragma unroll
          for (int mt = 0; mt < 4; ++mt)
            acc2[mt][nt] = __builtin_amdgcn_mfma_f32_16x16x32_bf16(afr[mt][ks], bfr, acc2[mt][nt], 0, 0, 0);
        }
      }
#pragma unroll
      for (int mt = 0; mt < 4; ++mt)
#pragma unroll
        for (int nt = 0; nt < 4; ++nt) {
          int col = wv * 64 + nt * 16 + lm;
#pragma unroll
          for (int r = 0; r < 4; ++r) {
            int ch = mt * 16 + lq * 4 + r;
            float v = fmaxf(acc2[mt][nt][r] + b2f[ch], 0.f);
            int u = (ch >> 3) ^ (col & 7);
            h2[(size_t)col * 64 + u * 8 + (ch & 7)] = f2bf(v);
          }
        }
    }
    __syncthreads();

    if (wv < 4) {
      f32x4 acc3[4][4];
#pragma unroll
      for (int mt = 0; mt < 4; ++mt)
#pragma unroll
        for (int nt = 0; nt < 4; ++nt) acc3[mt][nt] = z4;
      short8 afr[4][2];
#pragma unroll
      for (int mt = 0; mt < 4; ++mt)
#pragma unroll
        for (int ks = 0; ks < 2; ++ks)
          afr[mt][ks] = *(const short8*)(W3b + (mt * 16 + lm) * 64 + ks * 32 + lq * 8);
#pragma unroll
      for (int nt = 0; nt < 4; ++nt) {
        int col = wv * 64 + nt * 16 + lm;
#pragma unroll
        for (int ks = 0; ks < 2; ++ks) {
          int u = (ks * 4 + lq) ^ (col & 7);
          short8 bfr = *(short8*)(h2 + (size_t)col * 64 + u * 8);
#pragma unroll
          for (int mt = 0; mt < 4; ++mt)
            acc3[mt][nt] = __builtin_amdgcn_mfma_f32_16x16x32_bf16(afr[mt][ks], bfr, acc3[mt][nt], 0, 0, 0);
        }
      }
#pragma unroll
      for (int nt = 0; nt < 4; ++nt) {
        int pl = wv * 4 + nt;
        int p_ = h * 16 + pl;
        int s_ = lm;
#pragma unroll
        for (int mt = 0; mt < 4; ++mt)
#pragma unroll
          for (int r = 0; r < 4; ++r) {
            int w_ = mt * 16 + lq * 4 + r;
            float v = acc3[mt][nt][r] + b3f[w_];
            wbuf[(size_t)p_ * 1024 + (s_ >> 3) * 512 + w_ * 8 + (s_ & 7)] = f2bf(v);
          }
      }
    }
    __syncthreads();
  }

  f32x4 accY[2] = {z4, z4};

  for (int ci = 0; ci < 4; ++ci) {
    {
      int sl = t;
      int p_ = sl >> 4, s_ = sl & 15;
      int iv = idxbuf[sl];
      const unsigned short* src = featT + ((size_t)bb * Nn + iv) * 64 + ci * 16;
      uint4 d0 = *(const uint4*)(src);
      uint4 d1 = *(const uint4*)(src + 8);
      unsigned uu[8] = {d0.x, d0.y, d0.z, d0.w, d1.x, d1.y, d1.z, d1.w};
      size_t base = (size_t)p_ * 256 + (s_ >> 3) * 128 + (s_ & 7);
#pragma unroll
      for (int k = 0; k < 8; ++k) {
        gbuf[base + (2 * k) * 8]     = (unsigned short)(uu[k] & 0xffffu);
        gbuf[base + (2 * k + 1) * 8] = (unsigned short)(uu[k] >> 16);
      }
    }
    __syncthreads();

    for (int wi = 0; wi < 4; ++wi) {
      int q = ci * 4 + wi;
      int buf = q & 1;
#pragma unroll
      for (int pp = 0; pp < 4; ++pp) {
        int p_ = wv * 4 + pp;
        short8 afr = z8, bfr = z8;
        if (lq < 2) {
          afr = *(short8*)(wbuf + (size_t)p_ * 1024 + lq * 512 + (wi * 16 + lm) * 8);
          bfr = *(short8*)(gbuf + (size_t)p_ * 256 + lq * 128 + lm * 8);
        }
        f32x4 d = __builtin_amdgcn_mfma_f32_16x16x32_bf16(afr, bfr, z4, 0, 0, 0);
        int kkb = lm * 16 + lq * 4;
        int us = (kkb >> 3) ^ (p_ & 7);
        uint2 w2v;
        w2v.x = pack2(f2bf(d[0]), f2bf(d[1]));
        w2v.y = pack2(f2bf(d[2]), f2bf(d[3]));
        *(uint2*)(aggbuf + (size_t)buf * 8192 + (size_t)p_ * 256 + us * 8 + (kkb & 7)) = w2v;
      }
      __syncthreads();
#pragma unroll
      for (int ks = 0; ks < 8; ++ks) {
        short8 wfr = *(const short8*)(WfP + ((size_t)((q * 8 + ks) * 8 + wv)) * 512 + lane * 8);
#pragma unroll
        for (int mt = 0; mt < 2; ++mt) {
          int p16 = mt * 16 + lm;
          int u = (ks * 4 + lq) ^ (p16 & 7);
          short8 afr = *(const short8*)(aggbuf + (size_t)buf * 8192 + (size_t)p16 * 256 + u * 8);
          accY[mt] = __builtin_amdgcn_mfma_f32_16x16x32_bf16(afr, wfr, accY[mt], 0, 0, 0);
        }
      }
    }
  }

  {
    int o = wv * 16 + lm;
    float bo = bff[o];
#pragma unroll
    for (int mt = 0; mt < 2; ++mt) {
      f32x4 vv;
#pragma unroll
      for (int r = 0; r < 4; ++r) vv[r] = fmaxf(accY[mt][r] + bo, 0.f);
      int p_ = mt * 16 + lq * 4;
      float* dst = outp + ((size_t)bb * On + o) * Nn + n0 + p_;
      *(f32x4*)dst = vv;
    }
  }
}

// ---------------- host launch ----------------
extern "C" void kernel_launch(void* const* d_in, const int* in_sizes, int n_in,
                              void* d_out, int out_size, void* d_ws, size_t ws_size,
                              hipStream_t stream) {
  const float* xyz  = (const float*)d_in[0];
  const float* feat = (const float*)d_in[1];
  const int*   idx  = (const int*)d_in[2];
  const float* W1 = (const float*)d_in[3];
  const float* b1 = (const float*)d_in[4];
  const float* g1 = (const float*)d_in[5];
  const float* be1 = (const float*)d_in[6];
  const float* m1 = (const float*)d_in[7];
  const float* v1 = (const float*)d_in[8];
  const float* W2 = (const float*)d_in[9];
  const float* b2 = (const float*)d_in[10];
  const float* g2 = (const float*)d_in[11];
  const float* be2 = (const float*)d_in[12];
  const float* m2 = (const float*)d_in[13];
  const float* v2 = (const float*)d_in[14];
  const float* W3 = (const float*)d_in[15];
  const float* b3 = (const float*)d_in[16];
  const float* Wf = (const float*)d_in[17];
  const float* bf_ = (const float*)d_in[18];
  const float* gf = (const float*)d_in[19];
  const float* bef = (const float*)d_in[20];
  const float* mf = (const float*)d_in[21];
  const float* vf = (const float*)d_in[22];

  char* ws = (char*)d_ws;
  unsigned short* featT = (unsigned short*)(ws + WS_FEATT);
  unsigned short* WfP   = (unsigned short*)(ws + WS_WFP);
  float*          pf    = (float*)(ws + WS_PF);
  unsigned short* W2f   = (unsigned short*)(ws + WS_W2F);
  unsigned short* W3b   = (unsigned short*)(ws + WS_W3B);
  unsigned short* wg    = (unsigned short*)(ws + WS_WG);
  float* outp = (float*)d_out;

  hipLaunchKernelGGL(k_params, dim3(1), dim3(256), 0, stream,
                     W1, b1, g1, be1, m1, v1, W2, b2, g2, be2, m2, v2,
                     W3, b3, bf_, gf, bef, mf, vf, pf, W2f, W3b);
  hipLaunchKernelGGL(k_featT, dim3(Bn * (Nn / 64)), dim3(256), 0, stream, feat, featT);
  hipLaunchKernelGGL(k_wfp, dim3(2048), dim3(256), 0, stream, Wf, gf, vf, WfP);

  // adaptive slicing: wg holds sliceBlocks block-rows (64 KB each)
  long long avail = (long long)ws_size - (long long)WS_WG;
  int sliceBlocks = (avail > 0) ? (int)(avail / (long long)WG_PER_BLOCK) : 0;
  if (sliceBlocks > MAIN_BLOCKS) sliceBlocks = MAIN_BLOCKS;

  if (sliceBlocks >= 128) {
    int nslices = (MAIN_BLOCKS + sliceBlocks - 1) / sliceBlocks;
    sliceBlocks = (MAIN_BLOCKS + nslices - 1) / nslices;   // balance
    hipFuncSetAttribute(reinterpret_cast<const void*>(k_wnet),
                        hipFuncAttributeMaxDynamicSharedMemorySize, SMEM_WNET);
    hipFuncSetAttribute(reinterpret_cast<const void*>(k_final),
                        hipFuncAttributeMaxDynamicSharedMemorySize, SMEM_FINAL);
    for (int s = 0; s < MAIN_BLOCKS; s += sliceBlocks) {
      int nb = MAIN_BLOCKS - s;
      if (nb > sliceBlocks) nb = sliceBlocks;
      hipLaunchKernelGGL(k_wnet, dim3(nb), dim3(512), SMEM_WNET, stream,
                         xyz, idx, pf, W2f, W3b, wg, s);
      hipLaunchKernelGGL(k_final, dim3(nb), dim3(512), SMEM_FINAL, stream,
                         idx, featT, WfP, pf, wg, outp, s);
    }
  } else {
    hipFuncSetAttribute(reinterpret_cast<const void*>(k_main),
                        hipFuncAttributeMaxDynamicSharedMemorySize, SMEM_MAIN);
    hipLaunchKernelGGL(k_main, dim3(MAIN_BLOCKS), dim3(512), SMEM_MAIN, stream,
                       xyz, idx, featT, WfP, pf, W2f, W3b, outp);
  }
}

// Round 14
// 651.384 us; speedup vs baseline: 2.6575x; 2.6575x over previous
//
#include <hip/hip_runtime.h>
#include <cstdint>
#include <cstddef>

// ---------------- problem constants ----------------
#define EPSV 1e-5f
constexpr int Bn  = 4;
constexpr int Nn  = 32768;
constexpr int Cn  = 64;
constexpr int NSn = 16;
constexpr int On  = 128;
constexpr int Pn  = 32;                        // points per main block
constexpr int MAIN_BLOCKS = Bn * (Nn / Pn);    // 4096

typedef __attribute__((ext_vector_type(8))) short short8;   // 8 bf16 (4 VGPRs)
typedef __attribute__((ext_vector_type(4))) float f32x4;

static __device__ __forceinline__ unsigned short f2bf(float f) {
  union { float f; unsigned u; } v; v.f = f;
  unsigned r = v.u + 0x7fffu + ((v.u >> 16) & 1u);   // RNE
  return (unsigned short)(r >> 16);
}
static __device__ __forceinline__ unsigned pack2(unsigned short a, unsigned short b) {
  return (unsigned)a | ((unsigned)b << 16);
}

// ---------------- workspace layout (bytes) ----------------
constexpr size_t WS_FEATT = 0;                        // bf16 featT[B][N][64]  : 16 MB
constexpr size_t WS_WFP   = 16u * 1024 * 1024;        // bf16 packed Wf frags  : 1 MB
constexpr size_t WS_PF    = 17u * 1024 * 1024;        // f32 folded params
constexpr size_t WS_W2F   = WS_PF + 4096;             // bf16 64x64 (inv2-folded)
constexpr size_t WS_W3B   = WS_W2F + 8192;            // bf16 64x64
constexpr size_t WS_WG    = 18u * 1024 * 1024;        // bf16 weights slice (adaptive)
constexpr size_t WG_PER_BLOCK = (size_t)Pn * 1024 * 2;  // 64 KB per block-row

// pf (f32 index) layout: [0..255] W1f(64x4, inv1-folded, pad4) [256..319] b1f
// [320..383] b2f  [384..447] b3f  [448..575] bff
__global__ void k_params(const float* __restrict__ W1, const float* __restrict__ b1,
                         const float* __restrict__ g1, const float* __restrict__ be1,
                         const float* __restrict__ m1, const float* __restrict__ v1,
                         const float* __restrict__ W2, const float* __restrict__ b2,
                         const float* __restrict__ g2, const float* __restrict__ be2,
                         const float* __restrict__ m2, const float* __restrict__ v2,
                         const float* __restrict__ W3, const float* __restrict__ b3,
                         const float* __restrict__ bf_, const float* __restrict__ gf,
                         const float* __restrict__ bef, const float* __restrict__ mf,
                         const float* __restrict__ vf,
                         float* __restrict__ pf, unsigned short* __restrict__ W2f,
                         unsigned short* __restrict__ W3b) {
  int t = threadIdx.x;
  if (t < 64) {
    float inv1 = g1[t] * rsqrtf(v1[t] + EPSV);
    pf[t * 4 + 0] = W1[t * 3 + 0] * inv1;
    pf[t * 4 + 1] = W1[t * 3 + 1] * inv1;
    pf[t * 4 + 2] = W1[t * 3 + 2] * inv1;
    pf[t * 4 + 3] = 0.f;
    pf[256 + t] = b1[t] * inv1 + be1[t] - m1[t] * inv1;
    float inv2 = g2[t] * rsqrtf(v2[t] + EPSV);
    pf[320 + t] = b2[t] * inv2 + be2[t] - m2[t] * inv2;
    pf[384 + t] = b3[t];
    for (int k = 0; k < 64; ++k) {
      W2f[t * 64 + k] = f2bf(W2[t * 64 + k] * inv2);
      W3b[t * 64 + k] = f2bf(W3[t * 64 + k]);
    }
  }
  if (t < 128) {
    float invf = gf[t] * rsqrtf(vf[t] + EPSV);
    pf[448 + t] = bf_[t] * invf + bef[t] - mf[t] * invf;
  }
}

// ---------------- prep: feature (B,C,N) f32 -> featT (B,N,C) bf16 ----------------
__global__ void k_featT(const float* __restrict__ feat, unsigned short* __restrict__ featT) {
  int blk = blockIdx.x;              // 2048 = B * N/64
  int b = blk >> 9;
  int n0 = (blk & 511) << 6;
  __shared__ float tile[64][65];
  int t = threadIdx.x;
  int n_in = t & 63;
  int c4 = t >> 6;                   // 0..3
  const float* fb = feat + (size_t)b * Cn * Nn;
#pragma unroll
  for (int k = 0; k < 16; ++k) {
    int c = c4 * 16 + k;
    tile[c][n_in] = fb[(size_t)c * Nn + n0 + n_in];
  }
  __syncthreads();
  unsigned short* outp = featT + ((size_t)b * Nn + n0) * Cn;
  int cc = t & 63;
#pragma unroll
  for (int k = 0; k < 16; ++k) {
    int nn = c4 * 16 + k;
    outp[(size_t)nn * Cn + cc] = f2bf(tile[cc][nn]);
  }
}

// ---------------- prep: pack Wf*invf into B-fragment order (round-1 verified) ----
__global__ void k_wfp(const float* __restrict__ Wf, const float* __restrict__ gf,
                      const float* __restrict__ vf, unsigned short* __restrict__ WfP) {
  int e = blockIdx.x * 256 + threadIdx.x;      // 0..524287
  int rec = e >> 9, wi_ = e & 511;
  int l = wi_ >> 3, j = wi_ & 7;
  int q = rec >> 6, ks = (rec >> 3) & 7, ot = rec & 7;
  int o = ot * 16 + (l & 15);
  int kk = ks * 32 + (l >> 4) * 8 + j;
  int c = (q >> 2) * 16 + (kk >> 4);
  int w = (q & 3) * 16 + (kk & 15);
  float invf = gf[o] * rsqrtf(vf[o] + EPSV);
  WfP[e] = f2bf(Wf[(size_t)o * 4096 + c * 64 + w] * invf);
}

// ================= SPLIT PATH (adaptive slices) =================
// ---- k_wnet: round-8 VERBATIM (4 compute waves; layer-3 TRANSPOSED ->
// coalesced wg stores). Same wg layout [p][sh][w][klo] as k_final reads.
constexpr int SMEM_WNET = 73728;

__launch_bounds__(512, 4)
__global__ void k_wnet(const float* __restrict__ xyz, const int* __restrict__ idx,
                       const float* __restrict__ pf,
                       const unsigned short* __restrict__ W2f,
                       const unsigned short* __restrict__ W3b,
                       unsigned short* __restrict__ wg, int sliceStart) {
  extern __shared__ __align__(16) char smem[];
  unsigned short* h1 = (unsigned short*)(smem);
  unsigned short* h2 = (unsigned short*)(smem + 32768);
  float4* gxbuf = (float4*)(smem + 65536);

  const int t = threadIdx.x;
  const int lane = t & 63;
  const int wv = t >> 6;
  const int lq = lane >> 4;
  const int lm = lane & 15;
  const int blkFlat = sliceStart + blockIdx.x;
  const int bb = blkFlat >> 10;
  const int n0 = (blkFlat & 1023) * Pn;
  const size_t wgBase = (size_t)blockIdx.x * Pn * 1024;  // slice-local

  const float* W1f = pf;
  const float* b1f = pf + 256;
  const float* b2f = pf + 320;
  const f32x4 z4 = {0.f, 0.f, 0.f, 0.f};

  if (t < 256) {
    const float* xb = xyz + (size_t)bb * Nn * 3;
#pragma unroll
    for (int a = 0; a < 2; ++a) {
      int col = t + a * 256;
      int p_ = col >> 4, s_ = col & 15;
      int iv = idx[((size_t)bb * Nn + n0 + p_) * NSn + s_];
      float cx = xb[(size_t)(n0 + p_) * 3 + 0];
      float cy = xb[(size_t)(n0 + p_) * 3 + 1];
      float cz = xb[(size_t)(n0 + p_) * 3 + 2];
      gxbuf[col] = make_float4(xb[(size_t)iv * 3 + 0] - cx,
                               xb[(size_t)iv * 3 + 1] - cy,
                               xb[(size_t)iv * 3 + 2] - cz, 0.f);
    }
  }
  __syncthreads();

  for (int h = 0; h < 2; ++h) {
    if (wv < 4) {
#pragma unroll
      for (int a = 0; a < 8; ++a) {
        int aid = t + a * 256;
        int col = aid & 255;
        int oct = aid >> 8;
        float4 g = gxbuf[h * 256 + col];
        unsigned short vals[8];
#pragma unroll
        for (int jj = 0; jj < 8; ++jj) {
          int ch = oct * 8 + jj;
          float v = W1f[ch * 4 + 0] * g.x + W1f[ch * 4 + 1] * g.y +
                    W1f[ch * 4 + 2] * g.z + b1f[ch];
          vals[jj] = f2bf(fmaxf(v, 0.f));
        }
        int u = oct ^ (col & 7);
        uint4 wv4;
        wv4.x = pack2(vals[0], vals[1]); wv4.y = pack2(vals[2], vals[3]);
        wv4.z = pack2(vals[4], vals[5]); wv4.w = pack2(vals[6], vals[7]);
        *(uint4*)(h1 + (size_t)col * 64 + u * 8) = wv4;
      }
    }
    __syncthreads();

    if (wv < 4) {
      f32x4 acc2[4][4];
#pragma unroll
      for (int mt = 0; mt < 4; ++mt)
#pragma unroll
        for (int nt = 0; nt < 4; ++nt) acc2[mt][nt] = z4;
      short8 afr[4][2];
#pragma unroll
      for (int mt = 0; mt < 4; ++mt)
#pragma unroll
        for (int ks = 0; ks < 2; ++ks)
          afr[mt][ks] = *(const short8*)(W2f + (mt * 16 + lm) * 64 + ks * 32 + lq * 8);
#pragma unroll
      for (int nt = 0; nt < 4; ++nt) {
        int col = wv * 64 + nt * 16 + lm;
#pragma unroll
        for (int ks = 0; ks < 2; ++ks) {
          int u = (ks * 4 + lq) ^ (col & 7);
          short8 bfr = *(short8*)(h1 + (size_t)col * 64 + u * 8);
#pragma unroll
          for (int mt = 0; mt < 4; ++mt)
            acc2[mt][nt] = __builtin_amdgcn_mfma_f32_16x16x32_bf16(afr[mt][ks], bfr, acc2[mt][nt], 0, 0, 0);
        }
      }
#pragma unroll
      for (int mt = 0; mt < 4; ++mt)
#pragma unroll
        for (int nt = 0; nt < 4; ++nt) {
          int col = wv * 64 + nt * 16 + lm;
#pragma unroll
          for (int r = 0; r < 4; ++r) {
            int ch = mt * 16 + lq * 4 + r;
            float v = fmaxf(acc2[mt][nt][r] + b2f[ch], 0.f);
            int u = (ch >> 3) ^ (col & 7);
            h2[(size_t)col * 64 + u * 8 + (ch & 7)] = f2bf(v);
          }
        }
    }
    __syncthreads();

    if (wv < 4) {
      // layer3 TRANSPOSED: D'[s][w] = mfma(A=h2-colfrag, B=W3-rowfrag)
      f32x4 acc3[4][4];
#pragma unroll
      for (int mt = 0; mt < 4; ++mt)
#pragma unroll
        for (int nt = 0; nt < 4; ++nt) acc3[mt][nt] = z4;
      short8 afr[4][2];
      float  b3s[4];
#pragma unroll
      for (int mt = 0; mt < 4; ++mt) {
#pragma unroll
        for (int ks = 0; ks < 2; ++ks)
          afr[mt][ks] = *(const short8*)(W3b + (mt * 16 + lm) * 64 + ks * 32 + lq * 8);
        b3s[mt] = pf[384 + mt * 16 + lm];
      }
#pragma unroll
      for (int nt = 0; nt < 4; ++nt) {
        int col = wv * 64 + nt * 16 + lm;
#pragma unroll
        for (int ks = 0; ks < 2; ++ks) {
          int u = (ks * 4 + lq) ^ (col & 7);
          short8 bfr = *(short8*)(h2 + (size_t)col * 64 + u * 8);
#pragma unroll
          for (int mt = 0; mt < 4; ++mt)
            acc3[mt][nt] = __builtin_amdgcn_mfma_f32_16x16x32_bf16(bfr, afr[mt][ks], acc3[mt][nt], 0, 0, 0);
        }
      }
      // lane holds s=lq*4+r, w=mt*16+lm -> ONE uint2/mt, coalesced 256B/wave
#pragma unroll
      for (int nt = 0; nt < 4; ++nt) {
        int p_ = h * 16 + wv * 4 + nt;
        size_t pg = wgBase + (size_t)p_ * 1024;
#pragma unroll
        for (int mt = 0; mt < 4; ++mt) {
          float v0 = acc3[mt][nt][0] + b3s[mt];
          float v1 = acc3[mt][nt][1] + b3s[mt];
          float v2 = acc3[mt][nt][2] + b3s[mt];
          float v3 = acc3[mt][nt][3] + b3s[mt];
          uint2 w2v;
          w2v.x = pack2(f2bf(v0), f2bf(v1));
          w2v.y = pack2(f2bf(v2), f2bf(v3));
          *(uint2*)(wg + pg + (lq >> 1) * 512 + (mt * 16 + lm) * 8 + (lq & 1) * 4) = w2v;
        }
      }
    }
    __syncthreads();
  }
}

// ---- k_final (R14): round-8 structure + af-prefetch rotation. af[wi][pp] is
// ci-invariant; a 4-frag register window is consumed by chunk wi's agg and the
// NEXT chunk's wg loads are issued BEFORE the barrier (compiler cannot hoist
// global loads across __syncthreads), giving them a full GEMM phase of cover.
constexpr int SMEM_FINAL = 49664;

__launch_bounds__(512, 4)
__global__ void k_final(const int* __restrict__ idx,
                        const unsigned short* __restrict__ featT,
                        const unsigned short* __restrict__ WfP,
                        const float* __restrict__ pf,
                        const unsigned short* __restrict__ wg,
                        float* __restrict__ outp, int sliceStart) {
  extern __shared__ __align__(16) char smem[];
  unsigned short* gbuf   = (unsigned short*)(smem);
  unsigned short* aggbuf = (unsigned short*)(smem + 16896);

  const int t = threadIdx.x;
  const int lane = t & 63;
  const int wv = t >> 6;
  const int lq = lane >> 4;
  const int lm = lane & 15;
  const int blkFlat = sliceStart + blockIdx.x;
  const int bb = blkFlat >> 10;
  const int n0 = (blkFlat & 1023) * Pn;

  const short8 z8 = {0, 0, 0, 0, 0, 0, 0, 0};
  const f32x4  z4 = {0.f, 0.f, 0.f, 0.f};

  // prologue: this thread's own gather index (one column per thread)
  const int p0 = t >> 4, s0 = t & 15;
  const int iv = idx[((size_t)bb * Nn + n0 + p0) * NSn + s0];
  const unsigned short* fsrc = featT + ((size_t)bb * Nn + iv) * 64;
  // slice-local af base: wbuf formula with point index relative to slice
  const unsigned short* afbase = wg + ((size_t)blockIdx.x * Pn + wv * 4) * 1024
                                    + (lq & 1) * 512 + lm * 8;

  f32x4 accY[2] = {z4, z4};

  // af register window: preload chunk wi=0's fragments (in flight across the
  // first staging phase + barrier).
  short8 afc[4];
#pragma unroll
  for (int pp = 0; pp < 4; ++pp)
    afc[pp] = *(const short8*)(afbase + (size_t)pp * 1024);

  for (int ci = 0; ci < 4; ++ci) {
    // stage gbuf[p][sh][c][8], p-stride 264 (4-way instead of 16-way conflicts)
    {
      uint4 d0 = *(const uint4*)(fsrc + ci * 16);
      uint4 d1 = *(const uint4*)(fsrc + ci * 16 + 8);
      unsigned uu[8] = {d0.x, d0.y, d0.z, d0.w, d1.x, d1.y, d1.z, d1.w};
      size_t base = (size_t)p0 * 264 + (s0 >> 3) * 128 + (s0 & 7);
#pragma unroll
      for (int k = 0; k < 8; ++k) {
        gbuf[base + (2 * k) * 8]     = (unsigned short)(uu[k] & 0xffffu);
        gbuf[base + (2 * k + 1) * 8] = (unsigned short)(uu[k] >> 16);
      }
    }
    __syncthreads();

    // B-fragment hoist (wi-invariant): lane (c=lm, k=s=(lq&1)*8+j), zero for lq>=2
    short8 bfr[4];
#pragma unroll
    for (int pp = 0; pp < 4; ++pp) {
      int p_ = wv * 4 + pp;
      short8 v = *(short8*)(gbuf + (size_t)p_ * 264 + (lq & 1) * 128 + lm * 8);
      bfr[pp] = (lq < 2) ? v : z8;
    }

#pragma unroll
    for (int wi = 0; wi < 4; ++wi) {
      int q = ci * 4 + wi;
      int buf = q & 1;
      short8 wf[8];
#pragma unroll
      for (int ks = 0; ks < 4; ++ks)
        wf[ks] = *(const short8*)(WfP + ((size_t)((q * 8 + ks) * 8 + wv)) * 512 + lane * 8);
      // agg: 4 points, one padded-K MFMA each; af from the prefetched window
#pragma unroll
      for (int pp = 0; pp < 4; ++pp) {
        int p_ = wv * 4 + pp;
        short8 afr = (lq < 2) ? afc[pp] : z8;
        f32x4 d = __builtin_amdgcn_mfma_f32_16x16x32_bf16(afr, bfr[pp], z4, 0, 0, 0);
        int kkb = lm * 16 + lq * 4;
        int us = (kkb >> 3) ^ (p_ & 7);
        uint2 w2v;
        w2v.x = pack2(f2bf(d[0]), f2bf(d[1]));
        w2v.y = pack2(f2bf(d[2]), f2bf(d[3]));
        *(uint2*)(aggbuf + (size_t)buf * 8192 + (size_t)p_ * 256 + us * 8 + (kkb & 7)) = w2v;
      }
      // issue NEXT chunk's af loads BEFORE the barrier (wi-cyclic, ci-invariant;
      // wi==3 reloads wi=0 for the next ci). Latency hides under GEMM below.
      {
        int wn = (wi + 1) & 3;
#pragma unroll
        for (int pp = 0; pp < 4; ++pp)
          afc[pp] = *(const short8*)(afbase + (size_t)pp * 1024 + wn * 128);
      }
      __syncthreads();
#pragma unroll
      for (int ks = 4; ks < 8; ++ks)
        wf[ks] = *(const short8*)(WfP + ((size_t)((q * 8 + ks) * 8 + wv)) * 512 + lane * 8);
      // final GEMM chunk: K=256; wave owns o-tile ot = wv
#pragma unroll
      for (int ks = 0; ks < 8; ++ks) {
#pragma unroll
        for (int mt = 0; mt < 2; ++mt) {
          int p16 = mt * 16 + lm;
          int u = (ks * 4 + lq) ^ (p16 & 7);
          short8 afr = *(const short8*)(aggbuf + (size_t)buf * 8192 + (size_t)p16 * 256 + u * 8);
          accY[mt] = __builtin_amdgcn_mfma_f32_16x16x32_bf16(afr, wf[ks], accY[mt], 0, 0, 0);
        }
      }
      // no barrier: next chunk writes the other agg buffer
    }
  }

  // epilogue: y = relu(acc + bff[o]), store (B,O,N)
  {
    int o = wv * 16 + lm;
    float bo = pf[448 + o];
#pragma unroll
    for (int mt = 0; mt < 2; ++mt) {
      f32x4 vv;
#pragma unroll
      for (int r = 0; r < 4; ++r) vv[r] = fmaxf(accY[mt][r] + bo, 0.f);
      int p_ = mt * 16 + lq * 4;
      float* dst = outp + ((size_t)bb * On + o) * Nn + n0 + p_;
      *(f32x4*)dst = vv;
    }
  }
}

// ================= FALLBACK: round-4 fused kernel (verbatim) =================
constexpr int SMEM_MAIN = 141312;

__launch_bounds__(512, 1)
__global__ void k_main(const float* __restrict__ xyz, const int* __restrict__ idx,
                       const unsigned short* __restrict__ featT,
                       const unsigned short* __restrict__ WfP,
                       const float* __restrict__ pf,
                       const unsigned short* __restrict__ W2f,
                       const unsigned short* __restrict__ W3b,
                       float* __restrict__ outp) {
  extern __shared__ __align__(16) char smem[];
  unsigned short* wbuf   = (unsigned short*)(smem);
  unsigned short* h1     = (unsigned short*)(smem + 65536);
  unsigned short* gbuf   = (unsigned short*)(smem + 65536);
  unsigned short* h2     = (unsigned short*)(smem + 98304);
  unsigned short* aggbuf = (unsigned short*)(smem + 98304);
  float4* gxbuf = (float4*)(smem + 131072);
  int*    idxbuf = (int*)(smem + 139264);

  const int t = threadIdx.x;
  const int lane = t & 63;
  const int wv = t >> 6;
  const int lq = lane >> 4;
  const int lm = lane & 15;
  const int blk = blockIdx.x;
  const int bb = blk >> 10;
  const int n0 = (blk & 1023) * Pn;

  const float* W1f = pf;
  const float* b1f = pf + 256;
  const float* b2f = pf + 320;
  const float* b3f = pf + 384;
  const float* bff = pf + 448;

  const short8 z8 = {0, 0, 0, 0, 0, 0, 0, 0};
  const f32x4  z4 = {0.f, 0.f, 0.f, 0.f};

  if (t < 256) {
    const float* xb = xyz + (size_t)bb * Nn * 3;
#pragma unroll
    for (int a = 0; a < 2; ++a) {
      int col = t + a * 256;
      int p_ = col >> 4, s_ = col & 15;
      int iv = idx[((size_t)bb * Nn + n0 + p_) * NSn + s_];
      idxbuf[col] = iv;
      float cx = xb[(size_t)(n0 + p_) * 3 + 0];
      float cy = xb[(size_t)(n0 + p_) * 3 + 1];
      float cz = xb[(size_t)(n0 + p_) * 3 + 2];
      gxbuf[col] = make_float4(xb[(size_t)iv * 3 + 0] - cx,
                               xb[(size_t)iv * 3 + 1] - cy,
                               xb[(size_t)iv * 3 + 2] - cz, 0.f);
    }
  }
  __syncthreads();

  for (int h = 0; h < 2; ++h) {
    if (wv < 4) {
#pragma unroll
      for (int a = 0; a < 8; ++a) {
        int aid = t + a * 256;
        int col = aid & 255;
        int oct = aid >> 8;
        float4 g = gxbuf[h * 256 + col];
        unsigned short vals[8];
#pragma unroll
        for (int jj = 0; jj < 8; ++jj) {
          int ch = oct * 8 + jj;
          float v = W1f[ch * 4 + 0] * g.x + W1f[ch * 4 + 1] * g.y +
                    W1f[ch * 4 + 2] * g.z + b1f[ch];
          vals[jj] = f2bf(fmaxf(v, 0.f));
        }
        int u = oct ^ (col & 7);
        uint4 wv4;
        wv4.x = pack2(vals[0], vals[1]); wv4.y = pack2(vals[2], vals[3]);
        wv4.z = pack2(vals[4], vals[5]); wv4.w = pack2(vals[6], vals[7]);
        *(uint4*)(h1 + (size_t)col * 64 + u * 8) = wv4;
      }
    }
    __syncthreads();

    if (wv < 4) {
      f32x4 acc2[4][4];
#pragma unroll
      for (int mt = 0; mt < 4; ++mt)
#pragma unroll
        for (int nt = 0; nt < 4; ++nt) acc2[mt][nt] = z4;
      short8 afr[4][2];
#pragma unroll
      for (int mt = 0; mt < 4; ++mt)
#pragma unroll
        for (int ks = 0; ks < 2; ++ks)
          afr[mt][ks] = *(const short8*)(W2f + (mt * 16 + lm) * 64 + ks * 32 + lq * 8);
#pragma unroll
      for (int nt = 0; nt < 4; ++nt) {
        int col = wv * 64 + nt * 16 + lm;
#pragma unroll
        for (int ks = 0; ks < 2; ++ks) {
          int u = (ks * 4 + lq) ^ (col & 7);
          short8 bfr = *(short8*)(h1 + (size_t)col * 64 + u * 8);
#pragma unroll
          for (int mt = 0; mt < 4; ++mt)
            acc2[mt][nt] = __builtin_amdgcn_mfma_f32_16x16x32_bf16(afr[mt][ks], bfr, acc2[mt][nt], 0, 0, 0);
        }
      }
#pragma unroll
      for (int mt = 0; mt < 4; ++mt)
#pragma unroll
        for (int nt = 0; nt < 4; ++nt) {
          int col = wv * 64 + nt * 16 + lm;
#pragma unroll
          for (int r = 0; r < 4; ++r) {
            int ch = mt * 16 + lq * 4 + r;
            float v = fmaxf(acc2[mt][nt][r] + b2f[ch], 0.f);
            int u = (ch >> 3) ^ (col & 7);
            h2[(size_t)col * 64 + u * 8 + (ch & 7)] = f2bf(v);
          }
        }
    }
    __syncthreads();

    if (wv < 4) {
      f32x4 acc3[4][4];
#pragma unroll
      for (int mt = 0; mt < 4; ++mt)
#pragma unroll
        for (int nt = 0; nt < 4; ++nt) acc3[mt][nt] = z4;
      short8 afr[4][2];
#pragma unroll
      for (int mt = 0; mt < 4; ++mt)
#pragma unroll
        for (int ks = 0; ks < 2; ++ks)
          afr[mt][ks] = *(const short8*)(W3b + (mt * 16 + lm) * 64 + ks * 32 + lq * 8);
#pragma unroll
      for (int nt = 0; nt < 4; ++nt) {
        int col = wv * 64 + nt * 16 + lm;
#pragma unroll
        for (int ks = 0; ks < 2; ++ks) {
          int u = (ks * 4 + lq) ^ (col & 7);
          short8 bfr = *(short8*)(h2 + (size_t)col * 64 + u * 8);
#pragma unroll
          for (int mt = 0; mt < 4; ++mt)
            acc3[mt][nt] = __builtin_amdgcn_mfma_f32_16x16x32_bf16(afr[mt][ks], bfr, acc3[mt][nt], 0, 0, 0);
        }
      }
#pragma unroll
      for (int nt = 0; nt < 4; ++nt) {
        int pl = wv * 4 + nt;
        int p_ = h * 16 + pl;
        int s_ = lm;
#pragma unroll
        for (int mt = 0; mt < 4; ++mt)
#pragma unroll
          for (int r = 0; r < 4; ++r) {
            int w_ = mt * 16 + lq * 4 + r;
            float v = acc3[mt][nt][r] + b3f[w_];
            wbuf[(size_t)p_ * 1024 + (s_ >> 3) * 512 + w_ * 8 + (s_ & 7)] = f2bf(v);
          }
      }
    }
    __syncthreads();
  }

  f32x4 accY[2] = {z4, z4};

  for (int ci = 0; ci < 4; ++ci) {
    {
      int sl = t;
      int p_ = sl >> 4, s_ = sl & 15;
      int iv = idxbuf[sl];
      const unsigned short* src = featT + ((size_t)bb * Nn + iv) * 64 + ci * 16;
      uint4 d0 = *(const uint4*)(src);
      uint4 d1 = *(const uint4*)(src + 8);
      unsigned uu[8] = {d0.x, d0.y, d0.z, d0.w, d1.x, d1.y, d1.z, d1.w};
      size_t base = (size_t)p_ * 256 + (s_ >> 3) * 128 + (s_ & 7);
#pragma unroll
      for (int k = 0; k < 8; ++k) {
        gbuf[base + (2 * k) * 8]     = (unsigned short)(uu[k] & 0xffffu);
        gbuf[base + (2 * k + 1) * 8] = (unsigned short)(uu[k] >> 16);
      }
    }
    __syncthreads();

    for (int wi = 0; wi < 4; ++wi) {
      int q = ci * 4 + wi;
      int buf = q & 1;
#pragma unroll
      for (int pp = 0; pp < 4; ++pp) {
        int p_ = wv * 4 + pp;
        short8 afr = z8, bfr = z8;
        if (lq < 2) {
          afr = *(short8*)(wbuf + (size_t)p_ * 1024 + lq * 512 + (wi * 16 + lm) * 8);
          bfr = *(short8*)(gbuf + (size_t)p_ * 256 + lq * 128 + lm * 8);
        }
        f32x4 d = __builtin_amdgcn_mfma_f32_16x16x32_bf16(afr, bfr, z4, 0, 0, 0);
        int kkb = lm * 16 + lq * 4;
        int us = (kkb >> 3) ^ (p_ & 7);
        uint2 w2v;
        w2v.x = pack2(f2bf(d[0]), f2bf(d[1]));
        w2v.y = pack2(f2bf(d[2]), f2bf(d[3]));
        *(uint2*)(aggbuf + (size_t)buf * 8192 + (size_t)p_ * 256 + us * 8 + (kkb & 7)) = w2v;
      }
      __syncthreads();
#pragma unroll
      for (int ks = 0; ks < 8; ++ks) {
        short8 wfr = *(const short8*)(WfP + ((size_t)((q * 8 + ks) * 8 + wv)) * 512 + lane * 8);
#pragma unroll
        for (int mt = 0; mt < 2; ++mt) {
          int p16 = mt * 16 + lm;
          int u = (ks * 4 + lq) ^ (p16 & 7);
          short8 afr = *(const short8*)(aggbuf + (size_t)buf * 8192 + (size_t)p16 * 256 + u * 8);
          accY[mt] = __builtin_amdgcn_mfma_f32_16x16x32_bf16(afr, wfr, accY[mt], 0, 0, 0);
        }
      }
    }
  }

  {
    int o = wv * 16 + lm;
    float bo = bff[o];
#pragma unroll
    for (int mt = 0; mt < 2; ++mt) {
      f32x4 vv;
#pragma unroll
      for (int r = 0; r < 4; ++r) vv[r] = fmaxf(accY[mt][r] + bo, 0.f);
      int p_ = mt * 16 + lq * 4;
      float* dst = outp + ((size_t)bb * On + o) * Nn + n0 + p_;
      *(f32x4*)dst = vv;
    }
  }
}

// ---------------- host launch ----------------
extern "C" void kernel_launch(void* const* d_in, const int* in_sizes, int n_in,
                              void* d_out, int out_size, void* d_ws, size_t ws_size,
                              hipStream_t stream) {
  const float* xyz  = (const float*)d_in[0];
  const float* feat = (const float*)d_in[1];
  const int*   idx  = (const int*)d_in[2];
  const float* W1 = (const float*)d_in[3];
  const float* b1 = (const float*)d_in[4];
  const float* g1 = (const float*)d_in[5];
  const float* be1 = (const float*)d_in[6];
  const float* m1 = (const float*)d_in[7];
  const float* v1 = (const float*)d_in[8];
  const float* W2 = (const float*)d_in[9];
  const float* b2 = (const float*)d_in[10];
  const float* g2 = (const float*)d_in[11];
  const float* be2 = (const float*)d_in[12];
  const float* m2 = (const float*)d_in[13];
  const float* v2 = (const float*)d_in[14];
  const float* W3 = (const float*)d_in[15];
  const float* b3 = (const float*)d_in[16];
  const float* Wf = (const float*)d_in[17];
  const float* bf_ = (const float*)d_in[18];
  const float* gf = (const float*)d_in[19];
  const float* bef = (const float*)d_in[20];
  const float* mf = (const float*)d_in[21];
  const float* vf = (const float*)d_in[22];

  char* ws = (char*)d_ws;
  unsigned short* featT = (unsigned short*)(ws + WS_FEATT);
  unsigned short* WfP   = (unsigned short*)(ws + WS_WFP);
  float*          pf    = (float*)(ws + WS_PF);
  unsigned short* W2f   = (unsigned short*)(ws + WS_W2F);
  unsigned short* W3b   = (unsigned short*)(ws + WS_W3B);
  unsigned short* wg    = (unsigned short*)(ws + WS_WG);
  float* outp = (float*)d_out;

  hipLaunchKernelGGL(k_params, dim3(1), dim3(256), 0, stream,
                     W1, b1, g1, be1, m1, v1, W2, b2, g2, be2, m2, v2,
                     W3, b3, bf_, gf, bef, mf, vf, pf, W2f, W3b);
  hipLaunchKernelGGL(k_featT, dim3(Bn * (Nn / 64)), dim3(256), 0, stream, feat, featT);
  hipLaunchKernelGGL(k_wfp, dim3(2048), dim3(256), 0, stream, Wf, gf, vf, WfP);

  // adaptive slicing: wg holds sliceBlocks block-rows (64 KB each)
  long long avail = (long long)ws_size - (long long)WS_WG;
  int sliceBlocks = (avail > 0) ? (int)(avail / (long long)WG_PER_BLOCK) : 0;
  if (sliceBlocks > MAIN_BLOCKS) sliceBlocks = MAIN_BLOCKS;

  if (sliceBlocks >= 128) {
    int nslices = (MAIN_BLOCKS + sliceBlocks - 1) / sliceBlocks;
    sliceBlocks = (MAIN_BLOCKS + nslices - 1) / nslices;   // balance
    hipFuncSetAttribute(reinterpret_cast<const void*>(k_wnet),
                        hipFuncAttributeMaxDynamicSharedMemorySize, SMEM_WNET);
    hipFuncSetAttribute(reinterpret_cast<const void*>(k_final),
                        hipFuncAttributeMaxDynamicSharedMemorySize, SMEM_FINAL);
    for (int s = 0; s < MAIN_BLOCKS; s += sliceBlocks) {
      int nb = MAIN_BLOCKS - s;
      if (nb > sliceBlocks) nb = sliceBlocks;
      hipLaunchKernelGGL(k_wnet, dim3(nb), dim3(512), SMEM_WNET, stream,
                         xyz, idx, pf, W2f, W3b, wg, s);
      hipLaunchKernelGGL(k_final, dim3(nb), dim3(512), SMEM_FINAL, stream,
                         idx, featT, WfP, pf, wg, outp, s);
    }
  } else {
    hipFuncSetAttribute(reinterpret_cast<const void*>(k_main),
                        hipFuncAttributeMaxDynamicSharedMemorySize, SMEM_MAIN);
    hipLaunchKernelGGL(k_main, dim3(MAIN_BLOCKS), dim3(512), SMEM_MAIN, stream,
                       xyz, idx, featT, WfP, pf, W2f, W3b, outp);
  }
}

// Round 15
// 598.776 us; speedup vs baseline: 2.8910x; 1.0879x over previous
//
#include <hip/hip_runtime.h>
#include <cstdint>
#include <cstddef>

// ---------------- problem constants ----------------
#define EPSV 1e-5f
constexpr int Bn  = 4;
constexpr int Nn  = 32768;
constexpr int Cn  = 64;
constexpr int NSn = 16;
constexpr int On  = 128;
constexpr int Pn  = 32;                        // points per main block
constexpr int MAIN_BLOCKS = Bn * (Nn / Pn);    // 4096

typedef __attribute__((ext_vector_type(8))) short short8;   // 8 bf16 (4 VGPRs)
typedef __attribute__((ext_vector_type(4))) float f32x4;

static __device__ __forceinline__ unsigned short f2bf(float f) {
  union { float f; unsigned u; } v; v.f = f;
  unsigned r = v.u + 0x7fffu + ((v.u >> 16) & 1u);   // RNE
  return (unsigned short)(r >> 16);
}
static __device__ __forceinline__ unsigned pack2(unsigned short a, unsigned short b) {
  return (unsigned)a | ((unsigned)b << 16);
}

// ---------------- workspace layout (bytes) ----------------
constexpr size_t WS_FEATT = 0;                        // bf16 featT[B][N][64]  : 16 MB
constexpr size_t WS_WFP   = 16u * 1024 * 1024;        // bf16 packed Wf frags  : 1 MB
constexpr size_t WS_PF    = 17u * 1024 * 1024;        // f32 folded params
constexpr size_t WS_W2F   = WS_PF + 4096;             // bf16 64x64 (inv2-folded)
constexpr size_t WS_W3B   = WS_W2F + 8192;            // bf16 64x64
constexpr size_t WS_WG    = 18u * 1024 * 1024;        // bf16 weights slice (adaptive)
constexpr size_t WG_PER_BLOCK = (size_t)Pn * 1024 * 2;  // 64 KB per block-row

// pf (f32 index) layout: [0..255] W1f(64x4, inv1-folded, pad4) [256..319] b1f
// [320..383] b2f  [384..447] b3f  [448..575] bff
__global__ void k_params(const float* __restrict__ W1, const float* __restrict__ b1,
                         const float* __restrict__ g1, const float* __restrict__ be1,
                         const float* __restrict__ m1, const float* __restrict__ v1,
                         const float* __restrict__ W2, const float* __restrict__ b2,
                         const float* __restrict__ g2, const float* __restrict__ be2,
                         const float* __restrict__ m2, const float* __restrict__ v2,
                         const float* __restrict__ W3, const float* __restrict__ b3,
                         const float* __restrict__ bf_, const float* __restrict__ gf,
                         const float* __restrict__ bef, const float* __restrict__ mf,
                         const float* __restrict__ vf,
                         float* __restrict__ pf, unsigned short* __restrict__ W2f,
                         unsigned short* __restrict__ W3b) {
  int t = threadIdx.x;
  if (t < 64) {
    float inv1 = g1[t] * rsqrtf(v1[t] + EPSV);
    pf[t * 4 + 0] = W1[t * 3 + 0] * inv1;
    pf[t * 4 + 1] = W1[t * 3 + 1] * inv1;
    pf[t * 4 + 2] = W1[t * 3 + 2] * inv1;
    pf[t * 4 + 3] = 0.f;
    pf[256 + t] = b1[t] * inv1 + be1[t] - m1[t] * inv1;
    float inv2 = g2[t] * rsqrtf(v2[t] + EPSV);
    pf[320 + t] = b2[t] * inv2 + be2[t] - m2[t] * inv2;
    pf[384 + t] = b3[t];
    for (int k = 0; k < 64; ++k) {
      W2f[t * 64 + k] = f2bf(W2[t * 64 + k] * inv2);
      W3b[t * 64 + k] = f2bf(W3[t * 64 + k]);
    }
  }
  if (t < 128) {
    float invf = gf[t] * rsqrtf(vf[t] + EPSV);
    pf[448 + t] = bf_[t] * invf + bef[t] - mf[t] * invf;
  }
}

// ---------------- prep: feature (B,C,N) f32 -> featT (B,N,C) bf16 ----------------
__global__ void k_featT(const float* __restrict__ feat, unsigned short* __restrict__ featT) {
  int blk = blockIdx.x;              // 2048 = B * N/64
  int b = blk >> 9;
  int n0 = (blk & 511) << 6;
  __shared__ float tile[64][65];
  int t = threadIdx.x;
  int n_in = t & 63;
  int c4 = t >> 6;                   // 0..3
  const float* fb = feat + (size_t)b * Cn * Nn;
#pragma unroll
  for (int k = 0; k < 16; ++k) {
    int c = c4 * 16 + k;
    tile[c][n_in] = fb[(size_t)c * Nn + n0 + n_in];
  }
  __syncthreads();
  unsigned short* outp = featT + ((size_t)b * Nn + n0) * Cn;
  int cc = t & 63;
#pragma unroll
  for (int k = 0; k < 16; ++k) {
    int nn = c4 * 16 + k;
    outp[(size_t)nn * Cn + cc] = f2bf(tile[cc][nn]);
  }
}

// ---------------- prep: pack Wf*invf into B-fragment order (round-1 verified) ----
__global__ void k_wfp(const float* __restrict__ Wf, const float* __restrict__ gf,
                      const float* __restrict__ vf, unsigned short* __restrict__ WfP) {
  int e = blockIdx.x * 256 + threadIdx.x;      // 0..524287
  int rec = e >> 9, wi_ = e & 511;
  int l = wi_ >> 3, j = wi_ & 7;
  int q = rec >> 6, ks = (rec >> 3) & 7, ot = rec & 7;
  int o = ot * 16 + (l & 15);
  int kk = ks * 32 + (l >> 4) * 8 + j;
  int c = (q >> 2) * 16 + (kk >> 4);
  int w = (q & 3) * 16 + (kk & 15);
  float invf = gf[o] * rsqrtf(vf[o] + EPSV);
  WfP[e] = f2bf(Wf[(size_t)o * 4096 + c * 64 + w] * invf);
}

// ================= SPLIT PATH (adaptive slices) =================
// ---- k_wnet: WeightNet; layer-3 computed TRANSPOSED (operand swap) so the wg
// store is coalesced. Same wg layout [p][sh][w][klo] as k_final reads.
constexpr int SMEM_WNET = 73728;

__launch_bounds__(512, 4)
__global__ void k_wnet(const float* __restrict__ xyz, const int* __restrict__ idx,
                       const float* __restrict__ pf,
                       const unsigned short* __restrict__ W2f,
                       const unsigned short* __restrict__ W3b,
                       unsigned short* __restrict__ wg, int sliceStart) {
  extern __shared__ __align__(16) char smem[];
  unsigned short* h1 = (unsigned short*)(smem);
  unsigned short* h2 = (unsigned short*)(smem + 32768);
  float4* gxbuf = (float4*)(smem + 65536);

  const int t = threadIdx.x;
  const int lane = t & 63;
  const int wv = t >> 6;
  const int lq = lane >> 4;
  const int lm = lane & 15;
  const int blkFlat = sliceStart + blockIdx.x;
  const int bb = blkFlat >> 10;
  const int n0 = (blkFlat & 1023) * Pn;
  const size_t wgBase = (size_t)blockIdx.x * Pn * 1024;  // slice-local

  const float* W1f = pf;
  const float* b1f = pf + 256;
  const float* b2f = pf + 320;
  const f32x4 z4 = {0.f, 0.f, 0.f, 0.f};

  if (t < 256) {
    const float* xb = xyz + (size_t)bb * Nn * 3;
#pragma unroll
    for (int a = 0; a < 2; ++a) {
      int col = t + a * 256;
      int p_ = col >> 4, s_ = col & 15;
      int iv = idx[((size_t)bb * Nn + n0 + p_) * NSn + s_];
      float cx = xb[(size_t)(n0 + p_) * 3 + 0];
      float cy = xb[(size_t)(n0 + p_) * 3 + 1];
      float cz = xb[(size_t)(n0 + p_) * 3 + 2];
      gxbuf[col] = make_float4(xb[(size_t)iv * 3 + 0] - cx,
                               xb[(size_t)iv * 3 + 1] - cy,
                               xb[(size_t)iv * 3 + 2] - cz, 0.f);
    }
  }
  __syncthreads();

  for (int h = 0; h < 2; ++h) {
    if (wv < 4) {
#pragma unroll
      for (int a = 0; a < 8; ++a) {
        int aid = t + a * 256;
        int col = aid & 255;
        int oct = aid >> 8;
        float4 g = gxbuf[h * 256 + col];
        unsigned short vals[8];
#pragma unroll
        for (int jj = 0; jj < 8; ++jj) {
          int ch = oct * 8 + jj;
          float v = W1f[ch * 4 + 0] * g.x + W1f[ch * 4 + 1] * g.y +
                    W1f[ch * 4 + 2] * g.z + b1f[ch];
          vals[jj] = f2bf(fmaxf(v, 0.f));
        }
        int u = oct ^ (col & 7);
        uint4 wv4;
        wv4.x = pack2(vals[0], vals[1]); wv4.y = pack2(vals[2], vals[3]);
        wv4.z = pack2(vals[4], vals[5]); wv4.w = pack2(vals[6], vals[7]);
        *(uint4*)(h1 + (size_t)col * 64 + u * 8) = wv4;
      }
    }
    __syncthreads();

    if (wv < 4) {
      f32x4 acc2[4][4];
#pragma unroll
      for (int mt = 0; mt < 4; ++mt)
#pragma unroll
        for (int nt = 0; nt < 4; ++nt) acc2[mt][nt] = z4;
      short8 afr[4][2];
#pragma unroll
      for (int mt = 0; mt < 4; ++mt)
#pragma unroll
        for (int ks = 0; ks < 2; ++ks)
          afr[mt][ks] = *(const short8*)(W2f + (mt * 16 + lm) * 64 + ks * 32 + lq * 8);
#pragma unroll
      for (int nt = 0; nt < 4; ++nt) {
        int col = wv * 64 + nt * 16 + lm;
#pragma unroll
        for (int ks = 0; ks < 2; ++ks) {
          int u = (ks * 4 + lq) ^ (col & 7);
          short8 bfr = *(short8*)(h1 + (size_t)col * 64 + u * 8);
#pragma unroll
          for (int mt = 0; mt < 4; ++mt)
            acc2[mt][nt] = __builtin_amdgcn_mfma_f32_16x16x32_bf16(afr[mt][ks], bfr, acc2[mt][nt], 0, 0, 0);
        }
      }
#pragma unroll
      for (int mt = 0; mt < 4; ++mt)
#pragma unroll
        for (int nt = 0; nt < 4; ++nt) {
          int col = wv * 64 + nt * 16 + lm;
#pragma unroll
          for (int r = 0; r < 4; ++r) {
            int ch = mt * 16 + lq * 4 + r;
            float v = fmaxf(acc2[mt][nt][r] + b2f[ch], 0.f);
            int u = (ch >> 3) ^ (col & 7);
            h2[(size_t)col * 64 + u * 8 + (ch & 7)] = f2bf(v);
          }
        }
    }
    __syncthreads();

    if (wv < 4) {
      // layer3 TRANSPOSED: D'[s][w] = mfma(A=h2-colfrag, B=W3-rowfrag-as-Bt).
      f32x4 acc3[4][4];
#pragma unroll
      for (int mt = 0; mt < 4; ++mt)
#pragma unroll
        for (int nt = 0; nt < 4; ++nt) acc3[mt][nt] = z4;
      short8 afr[4][2];
      float  b3s[4];
#pragma unroll
      for (int mt = 0; mt < 4; ++mt) {
#pragma unroll
        for (int ks = 0; ks < 2; ++ks)
          afr[mt][ks] = *(const short8*)(W3b + (mt * 16 + lm) * 64 + ks * 32 + lq * 8);
        b3s[mt] = pf[384 + mt * 16 + lm];
      }
#pragma unroll
      for (int nt = 0; nt < 4; ++nt) {
        int col = wv * 64 + nt * 16 + lm;
#pragma unroll
        for (int ks = 0; ks < 2; ++ks) {
          int u = (ks * 4 + lq) ^ (col & 7);
          short8 bfr = *(short8*)(h2 + (size_t)col * 64 + u * 8);
#pragma unroll
          for (int mt = 0; mt < 4; ++mt)
            acc3[mt][nt] = __builtin_amdgcn_mfma_f32_16x16x32_bf16(bfr, afr[mt][ks], acc3[mt][nt], 0, 0, 0);
        }
      }
      // lane holds s=lq*4+r, w=mt*16+lm -> ONE uint2/mt, coalesced 256B/wave
#pragma unroll
      for (int nt = 0; nt < 4; ++nt) {
        int p_ = h * 16 + wv * 4 + nt;
        size_t pg = wgBase + (size_t)p_ * 1024;
#pragma unroll
        for (int mt = 0; mt < 4; ++mt) {
          float v0 = acc3[mt][nt][0] + b3s[mt];
          float v1 = acc3[mt][nt][1] + b3s[mt];
          float v2 = acc3[mt][nt][2] + b3s[mt];
          float v3 = acc3[mt][nt][3] + b3s[mt];
          uint2 w2v;
          w2v.x = pack2(f2bf(v0), f2bf(v1));
          w2v.y = pack2(f2bf(v2), f2bf(v3));
          *(uint2*)(wg + pg + (lq >> 1) * 512 + (mt * 16 + lm) * 8 + (lq & 1) * 4) = w2v;
        }
      }
    }
    __syncthreads();
  }
}

// ---- k_final: round-8 phase-D formulas; af from global wg slice, gbuf padded
// [32p][264] (round-5 verified), bfr hoist (round-5 verified), Wf 4+4 prefetch.
// LDS: gbuf 16896 + aggbuf 32768 = 49664 B -> 2 blocks/CU.
constexpr int SMEM_FINAL = 49664;

__launch_bounds__(512, 4)
__global__ void k_final(const int* __restrict__ idx,
                        const unsigned short* __restrict__ featT,
                        const unsigned short* __restrict__ WfP,
                        const float* __restrict__ pf,
                        const unsigned short* __restrict__ wg,
                        float* __restrict__ outp, int sliceStart) {
  extern __shared__ __align__(16) char smem[];
  unsigned short* gbuf   = (unsigned short*)(smem);
  unsigned short* aggbuf = (unsigned short*)(smem + 16896);

  const int t = threadIdx.x;
  const int lane = t & 63;
  const int wv = t >> 6;
  const int lq = lane >> 4;
  const int lm = lane & 15;
  const int blkFlat = sliceStart + blockIdx.x;
  const int bb = blkFlat >> 10;
  const int n0 = (blkFlat & 1023) * Pn;

  const short8 z8 = {0, 0, 0, 0, 0, 0, 0, 0};
  const f32x4  z4 = {0.f, 0.f, 0.f, 0.f};

  // prologue: this thread's own gather index (one column per thread)
  const int p0 = t >> 4, s0 = t & 15;
  const int iv = idx[((size_t)bb * Nn + n0 + p0) * NSn + s0];
  const unsigned short* fsrc = featT + ((size_t)bb * Nn + iv) * 64;
  // slice-local af base: wbuf formula with point index relative to slice
  const unsigned short* afbase = wg + ((size_t)blockIdx.x * Pn + wv * 4) * 1024
                                    + (lq & 1) * 512 + lm * 8;

  f32x4 accY[2] = {z4, z4};

  for (int ci = 0; ci < 4; ++ci) {
    // stage gbuf[p][sh][c][8], p-stride 264 (4-way instead of 16-way conflicts)
    {
      uint4 d0 = *(const uint4*)(fsrc + ci * 16);
      uint4 d1 = *(const uint4*)(fsrc + ci * 16 + 8);
      unsigned uu[8] = {d0.x, d0.y, d0.z, d0.w, d1.x, d1.y, d1.z, d1.w};
      size_t base = (size_t)p0 * 264 + (s0 >> 3) * 128 + (s0 & 7);
#pragma unroll
      for (int k = 0; k < 8; ++k) {
        gbuf[base + (2 * k) * 8]     = (unsigned short)(uu[k] & 0xffffu);
        gbuf[base + (2 * k + 1) * 8] = (unsigned short)(uu[k] >> 16);
      }
    }
    __syncthreads();

    // B-fragment hoist (wi-invariant): lane (c=lm, k=s=(lq&1)*8+j), zero for lq>=2
    short8 bfr[4];
#pragma unroll
    for (int pp = 0; pp < 4; ++pp) {
      int p_ = wv * 4 + pp;
      short8 v = *(short8*)(gbuf + (size_t)p_ * 264 + (lq & 1) * 128 + lm * 8);
      bfr[pp] = (lq < 2) ? v : z8;
    }

#pragma unroll
    for (int wi = 0; wi < 4; ++wi) {
      int q = ci * 4 + wi;
      int buf = q & 1;
      short8 wf[8];
#pragma unroll
      for (int ks = 0; ks < 4; ++ks)
        wf[ks] = *(const short8*)(WfP + ((size_t)((q * 8 + ks) * 8 + wv)) * 512 + lane * 8);
      // agg: 4 points, one padded-K MFMA each; af straight from global wg
#pragma unroll
      for (int pp = 0; pp < 4; ++pp) {
        int p_ = wv * 4 + pp;
        short8 afv = *(const short8*)(afbase + (size_t)pp * 1024 + wi * 128);
        short8 afr = (lq < 2) ? afv : z8;
        f32x4 d = __builtin_amdgcn_mfma_f32_16x16x32_bf16(afr, bfr[pp], z4, 0, 0, 0);
        int kkb = lm * 16 + lq * 4;
        int us = (kkb >> 3) ^ (p_ & 7);
        uint2 w2v;
        w2v.x = pack2(f2bf(d[0]), f2bf(d[1]));
        w2v.y = pack2(f2bf(d[2]), f2bf(d[3]));
        *(uint2*)(aggbuf + (size_t)buf * 8192 + (size_t)p_ * 256 + us * 8 + (kkb & 7)) = w2v;
      }
      __syncthreads();
#pragma unroll
      for (int ks = 4; ks < 8; ++ks)
        wf[ks] = *(const short8*)(WfP + ((size_t)((q * 8 + ks) * 8 + wv)) * 512 + lane * 8);
      // final GEMM chunk: K=256; wave owns o-tile ot = wv
#pragma unroll
      for (int ks = 0; ks < 8; ++ks) {
#pragma unroll
        for (int mt = 0; mt < 2; ++mt) {
          int p16 = mt * 16 + lm;
          int u = (ks * 4 + lq) ^ (p16 & 7);
          short8 afr = *(const short8*)(aggbuf + (size_t)buf * 8192 + (size_t)p16 * 256 + u * 8);
          accY[mt] = __builtin_amdgcn_mfma_f32_16x16x32_bf16(afr, wf[ks], accY[mt], 0, 0, 0);
        }
      }
      // no barrier: next chunk writes the other agg buffer
    }
  }

  // epilogue: y = relu(acc + bff[o]), store (B,O,N)
  {
    int o = wv * 16 + lm;
    float bo = pf[448 + o];
#pragma unroll
    for (int mt = 0; mt < 2; ++mt) {
      f32x4 vv;
#pragma unroll
      for (int r = 0; r < 4; ++r) vv[r] = fmaxf(accY[mt][r] + bo, 0.f);
      int p_ = mt * 16 + lq * 4;
      float* dst = outp + ((size_t)bb * On + o) * Nn + n0 + p_;
      *(f32x4*)dst = vv;
    }
  }
}

// ================= FALLBACK: round-4 fused kernel (verbatim) =================
constexpr int SMEM_MAIN = 141312;

__launch_bounds__(512, 1)
__global__ void k_main(const float* __restrict__ xyz, const int* __restrict__ idx,
                       const unsigned short* __restrict__ featT,
                       const unsigned short* __restrict__ WfP,
                       const float* __restrict__ pf,
                       const unsigned short* __restrict__ W2f,
                       const unsigned short* __restrict__ W3b,
                       float* __restrict__ outp) {
  extern __shared__ __align__(16) char smem[];
  unsigned short* wbuf   = (unsigned short*)(smem);
  unsigned short* h1     = (unsigned short*)(smem + 65536);
  unsigned short* gbuf   = (unsigned short*)(smem + 65536);
  unsigned short* h2     = (unsigned short*)(smem + 98304);
  unsigned short* aggbuf = (unsigned short*)(smem + 98304);
  float4* gxbuf = (float4*)(smem + 131072);
  int*    idxbuf = (int*)(smem + 139264);

  const int t = threadIdx.x;
  const int lane = t & 63;
  const int wv = t >> 6;
  const int lq = lane >> 4;
  const int lm = lane & 15;
  const int blk = blockIdx.x;
  const int bb = blk >> 10;
  const int n0 = (blk & 1023) * Pn;

  const float* W1f = pf;
  const float* b1f = pf + 256;
  const float* b2f = pf + 320;
  const float* b3f = pf + 384;
  const float* bff = pf + 448;

  const short8 z8 = {0, 0, 0, 0, 0, 0, 0, 0};
  const f32x4  z4 = {0.f, 0.f, 0.f, 0.f};

  if (t < 256) {
    const float* xb = xyz + (size_t)bb * Nn * 3;
#pragma unroll
    for (int a = 0; a < 2; ++a) {
      int col = t + a * 256;
      int p_ = col >> 4, s_ = col & 15;
      int iv = idx[((size_t)bb * Nn + n0 + p_) * NSn + s_];
      idxbuf[col] = iv;
      float cx = xb[(size_t)(n0 + p_) * 3 + 0];
      float cy = xb[(size_t)(n0 + p_) * 3 + 1];
      float cz = xb[(size_t)(n0 + p_) * 3 + 2];
      gxbuf[col] = make_float4(xb[(size_t)iv * 3 + 0] - cx,
                               xb[(size_t)iv * 3 + 1] - cy,
                               xb[(size_t)iv * 3 + 2] - cz, 0.f);
    }
  }
  __syncthreads();

  for (int h = 0; h < 2; ++h) {
    if (wv < 4) {
#pragma unroll
      for (int a = 0; a < 8; ++a) {
        int aid = t + a * 256;
        int col = aid & 255;
        int oct = aid >> 8;
        float4 g = gxbuf[h * 256 + col];
        unsigned short vals[8];
#pragma unroll
        for (int jj = 0; jj < 8; ++jj) {
          int ch = oct * 8 + jj;
          float v = W1f[ch * 4 + 0] * g.x + W1f[ch * 4 + 1] * g.y +
                    W1f[ch * 4 + 2] * g.z + b1f[ch];
          vals[jj] = f2bf(fmaxf(v, 0.f));
        }
        int u = oct ^ (col & 7);
        uint4 wv4;
        wv4.x = pack2(vals[0], vals[1]); wv4.y = pack2(vals[2], vals[3]);
        wv4.z = pack2(vals[4], vals[5]); wv4.w = pack2(vals[6], vals[7]);
        *(uint4*)(h1 + (size_t)col * 64 + u * 8) = wv4;
      }
    }
    __syncthreads();

    if (wv < 4) {
      f32x4 acc2[4][4];
#pragma unroll
      for (int mt = 0; mt < 4; ++mt)
#pragma unroll
        for (int nt = 0; nt < 4; ++nt) acc2[mt][nt] = z4;
      short8 afr[4][2];
#pragma unroll
      for (int mt = 0; mt < 4; ++mt)
#pragma unroll
        for (int ks = 0; ks < 2; ++ks)
          afr[mt][ks] = *(const short8*)(W2f + (mt * 16 + lm) * 64 + ks * 32 + lq * 8);
#pragma unroll
      for (int nt = 0; nt < 4; ++nt) {
        int col = wv * 64 + nt * 16 + lm;
#pragma unroll
        for (int ks = 0; ks < 2; ++ks) {
          int u = (ks * 4 + lq) ^ (col & 7);
          short8 bfr = *(short8*)(h1 + (size_t)col * 64 + u * 8);
#pragma unroll
          for (int mt = 0; mt < 4; ++mt)
            acc2[mt][nt] = __builtin_amdgcn_mfma_f32_16x16x32_bf16(afr[mt][ks], bfr, acc2[mt][nt], 0, 0, 0);
        }
      }
#pragma unroll
      for (int mt = 0; mt < 4; ++mt)
#pragma unroll
        for (int nt = 0; nt < 4; ++nt) {
          int col = wv * 64 + nt * 16 + lm;
#pragma unroll
          for (int r = 0; r < 4; ++r) {
            int ch = mt * 16 + lq * 4 + r;
            float v = fmaxf(acc2[mt][nt][r] + b2f[ch], 0.f);
            int u = (ch >> 3) ^ (col & 7);
            h2[(size_t)col * 64 + u * 8 + (ch & 7)] = f2bf(v);
          }
        }
    }
    __syncthreads();

    if (wv < 4) {
      f32x4 acc3[4][4];
#pragma unroll
      for (int mt = 0; mt < 4; ++mt)
#pragma unroll
        for (int nt = 0; nt < 4; ++nt) acc3[mt][nt] = z4;
      short8 afr[4][2];
#pragma unroll
      for (int mt = 0; mt < 4; ++mt)
#pragma unroll
        for (int ks = 0; ks < 2; ++ks)
          afr[mt][ks] = *(const short8*)(W3b + (mt * 16 + lm) * 64 + ks * 32 + lq * 8);
#pragma unroll
      for (int nt = 0; nt < 4; ++nt) {
        int col = wv * 64 + nt * 16 + lm;
#pragma unroll
        for (int ks = 0; ks < 2; ++ks) {
          int u = (ks * 4 + lq) ^ (col & 7);
          short8 bfr = *(short8*)(h2 + (size_t)col * 64 + u * 8);
#pragma unroll
          for (int mt = 0; mt < 4; ++mt)
            acc3[mt][nt] = __builtin_amdgcn_mfma_f32_16x16x32_bf16(afr[mt][ks], bfr, acc3[mt][nt], 0, 0, 0);
        }
      }
#pragma unroll
      for (int nt = 0; nt < 4; ++nt) {
        int pl = wv * 4 + nt;
        int p_ = h * 16 + pl;
        int s_ = lm;
#pragma unroll
        for (int mt = 0; mt < 4; ++mt)
#pragma unroll
          for (int r = 0; r < 4; ++r) {
            int w_ = mt * 16 + lq * 4 + r;
            float v = acc3[mt][nt][r] + b3f[w_];
            wbuf[(size_t)p_ * 1024 + (s_ >> 3) * 512 + w_ * 8 + (s_ & 7)] = f2bf(v);
          }
      }
    }
    __syncthreads();
  }

  f32x4 accY[2] = {z4, z4};

  for (int ci = 0; ci < 4; ++ci) {
    {
      int sl = t;
      int p_ = sl >> 4, s_ = sl & 15;
      int iv = idxbuf[sl];
      const unsigned short* src = featT + ((size_t)bb * Nn + iv) * 64 + ci * 16;
      uint4 d0 = *(const uint4*)(src);
      uint4 d1 = *(const uint4*)(src + 8);
      unsigned uu[8] = {d0.x, d0.y, d0.z, d0.w, d1.x, d1.y, d1.z, d1.w};
      size_t base = (size_t)p_ * 256 + (s_ >> 3) * 128 + (s_ & 7);
#pragma unroll
      for (int k = 0; k < 8; ++k) {
        gbuf[base + (2 * k) * 8]     = (unsigned short)(uu[k] & 0xffffu);
        gbuf[base + (2 * k + 1) * 8] = (unsigned short)(uu[k] >> 16);
      }
    }
    __syncthreads();

    for (int wi = 0; wi < 4; ++wi) {
      int q = ci * 4 + wi;
      int buf = q & 1;
#pragma unroll
      for (int pp = 0; pp < 4; ++pp) {
        int p_ = wv * 4 + pp;
        short8 afr = z8, bfr = z8;
        if (lq < 2) {
          afr = *(short8*)(wbuf + (size_t)p_ * 1024 + lq * 512 + (wi * 16 + lm) * 8);
          bfr = *(short8*)(gbuf + (size_t)p_ * 256 + lq * 128 + lm * 8);
        }
        f32x4 d = __builtin_amdgcn_mfma_f32_16x16x32_bf16(afr, bfr, z4, 0, 0, 0);
        int kkb = lm * 16 + lq * 4;
        int us = (kkb >> 3) ^ (p_ & 7);
        uint2 w2v;
        w2v.x = pack2(f2bf(d[0]), f2bf(d[1]));
        w2v.y = pack2(f2bf(d[2]), f2bf(d[3]));
        *(uint2*)(aggbuf + (size_t)buf * 8192 + (size_t)p_ * 256 + us * 8 + (kkb & 7)) = w2v;
      }
      __syncthreads();
#pragma unroll
      for (int ks = 0; ks < 8; ++ks) {
        short8 wfr = *(const short8*)(WfP + ((size_t)((q * 8 + ks) * 8 + wv)) * 512 + lane * 8);
#pragma unroll
        for (int mt = 0; mt < 2; ++mt) {
          int p16 = mt * 16 + lm;
          int u = (ks * 4 + lq) ^ (p16 & 7);
          short8 afr = *(const short8*)(aggbuf + (size_t)buf * 8192 + (size_t)p16 * 256 + u * 8);
          accY[mt] = __builtin_amdgcn_mfma_f32_16x16x32_bf16(afr, wfr, accY[mt], 0, 0, 0);
        }
      }
    }
  }

  {
    int o = wv * 16 + lm;
    float bo = bff[o];
#pragma unroll
    for (int mt = 0; mt < 2; ++mt) {
      f32x4 vv;
#pragma unroll
      for (int r = 0; r < 4; ++r) vv[r] = fmaxf(accY[mt][r] + bo, 0.f);
      int p_ = mt * 16 + lq * 4;
      float* dst = outp + ((size_t)bb * On + o) * Nn + n0 + p_;
      *(f32x4*)dst = vv;
    }
  }
}

// ---------------- host launch ----------------
extern "C" void kernel_launch(void* const* d_in, const int* in_sizes, int n_in,
                              void* d_out, int out_size, void* d_ws, size_t ws_size,
                              hipStream_t stream) {
  const float* xyz  = (const float*)d_in[0];
  const float* feat = (const float*)d_in[1];
  const int*   idx  = (const int*)d_in[2];
  const float* W1 = (const float*)d_in[3];
  const float* b1 = (const float*)d_in[4];
  const float* g1 = (const float*)d_in[5];
  const float* be1 = (const float*)d_in[6];
  const float* m1 = (const float*)d_in[7];
  const float* v1 = (const float*)d_in[8];
  const float* W2 = (const float*)d_in[9];
  const float* b2 = (const float*)d_in[10];
  const float* g2 = (const float*)d_in[11];
  const float* be2 = (const float*)d_in[12];
  const float* m2 = (const float*)d_in[13];
  const float* v2 = (const float*)d_in[14];
  const float* W3 = (const float*)d_in[15];
  const float* b3 = (const float*)d_in[16];
  const float* Wf = (const float*)d_in[17];
  const float* bf_ = (const float*)d_in[18];
  const float* gf = (const float*)d_in[19];
  const float* bef = (const float*)d_in[20];
  const float* mf = (const float*)d_in[21];
  const float* vf = (const float*)d_in[22];

  char* ws = (char*)d_ws;
  unsigned short* featT = (unsigned short*)(ws + WS_FEATT);
  unsigned short* WfP   = (unsigned short*)(ws + WS_WFP);
  float*          pf    = (float*)(ws + WS_PF);
  unsigned short* W2f   = (unsigned short*)(ws + WS_W2F);
  unsigned short* W3b   = (unsigned short*)(ws + WS_W3B);
  unsigned short* wg    = (unsigned short*)(ws + WS_WG);
  float* outp = (float*)d_out;

  hipLaunchKernelGGL(k_params, dim3(1), dim3(256), 0, stream,
                     W1, b1, g1, be1, m1, v1, W2, b2, g2, be2, m2, v2,
                     W3, b3, bf_, gf, bef, mf, vf, pf, W2f, W3b);
  hipLaunchKernelGGL(k_featT, dim3(Bn * (Nn / 64)), dim3(256), 0, stream, feat, featT);
  hipLaunchKernelGGL(k_wfp, dim3(2048), dim3(256), 0, stream, Wf, gf, vf, WfP);

  // adaptive slicing: wg holds sliceBlocks block-rows (64 KB each)
  long long avail = (long long)ws_size - (long long)WS_WG;
  int sliceBlocks = (avail > 0) ? (int)(avail / (long long)WG_PER_BLOCK) : 0;
  if (sliceBlocks > MAIN_BLOCKS) sliceBlocks = MAIN_BLOCKS;

  if (sliceBlocks >= 128) {
    int nslices = (MAIN_BLOCKS + sliceBlocks - 1) / sliceBlocks;
    sliceBlocks = (MAIN_BLOCKS + nslices - 1) / nslices;   // balance
    hipFuncSetAttribute(reinterpret_cast<const void*>(k_wnet),
                        hipFuncAttributeMaxDynamicSharedMemorySize, SMEM_WNET);
    hipFuncSetAttribute(reinterpret_cast<const void*>(k_final),
                        hipFuncAttributeMaxDynamicSharedMemorySize, SMEM_FINAL);
    for (int s = 0; s < MAIN_BLOCKS; s += sliceBlocks) {
      int nb = MAIN_BLOCKS - s;
      if (nb > sliceBlocks) nb = sliceBlocks;
      hipLaunchKernelGGL(k_wnet, dim3(nb), dim3(512), SMEM_WNET, stream,
                         xyz, idx, pf, W2f, W3b, wg, s);
      hipLaunchKernelGGL(k_final, dim3(nb), dim3(512), SMEM_FINAL, stream,
                         idx, featT, WfP, pf, wg, outp, s);
    }
  } else {
    hipFuncSetAttribute(reinterpret_cast<const void*>(k_main),
                        hipFuncAttributeMaxDynamicSharedMemorySize, SMEM_MAIN);
    hipLaunchKernelGGL(k_main, dim3(MAIN_BLOCKS), dim3(512), SMEM_MAIN, stream,
                       xyz, idx, featT, WfP, pf, W2f, W3b, outp);
  }
}